// Round 15
// baseline (592.094 us; speedup 1.0000x reference)
//
#include <hip/hip_runtime.h>
#include <cstdint>
#include <cstddef>

#define D 1024
#define LSEQ 2048
#define BATCH 8
#define NCHUNK 32   // LSEQ / 64

typedef float fx4  __attribute__((ext_vector_type(4)));
typedef short s16x8 __attribute__((ext_vector_type(8)));
typedef short s16x4 __attribute__((ext_vector_type(4)));

static __device__ __forceinline__ short f2bf(float f) {
  unsigned u = __builtin_bit_cast(unsigned, f);
  u = (u + 0x7FFFu + ((u >> 16) & 1u)) >> 16;   // RNE (finite values)
  return (short)u;
}
static __device__ __forceinline__ float bf2f(unsigned short h) {
  unsigned u = ((unsigned)h) << 16;
  return __builtin_bit_cast(float, u);
}

// ---------------------------------------------------------------------------
// Fused: xh = bf16(x) AND beta = sigmoid(x . Wb). One wave per row.
// ---------------------------------------------------------------------------
__global__ __launch_bounds__(256)
void packbeta(const float* __restrict__ x, const float* __restrict__ Wb,
              short* __restrict__ xh, float* __restrict__ betao) {
  const int lane = threadIdx.x & 63;
  const int w = threadIdx.x >> 6;
  const size_t row = (size_t)blockIdx.x * 4 + w;
  float s = 0.f;
#pragma unroll
  for (int m = 0; m < 4; ++m) {
    float4 xv = *(const float4*)&x[row * D + m * 256 + lane * 4];
    float4 wv = *(const float4*)&Wb[m * 256 + lane * 4];
    s += xv.x * wv.x + xv.y * wv.y + xv.z * wv.z + xv.w * wv.w;
    s16x4 p;
    p[0] = f2bf(xv.x); p[1] = f2bf(xv.y); p[2] = f2bf(xv.z); p[3] = f2bf(xv.w);
    *(s16x4*)(xh + row * D + m * 256 + lane * 4) = p;
  }
#pragma unroll
  for (int d = 1; d < 64; d <<= 1) s += __shfl_xor(s, d, 64);
  if (lane == 0) betao[row] = 1.f / (1.f + expf(-s));
}

// ---------------------------------------------------------------------------
// W [K][N] fp32 -> WT [N][K] bf16, 64x64 tiles via LDS; z selects one of 3 W.
// ---------------------------------------------------------------------------
__global__ __launch_bounds__(256)
void wtrans3(const float* __restrict__ W0, const float* __restrict__ W1,
             const float* __restrict__ W2, short* __restrict__ WTb) {
  __shared__ short Tl[64][66];
  const float* W = blockIdx.z == 0 ? W0 : (blockIdx.z == 1 ? W1 : W2);
  short* WT = WTb + (size_t)blockIdx.z * D * D;
  const int nt = blockIdx.x, kt0 = blockIdx.y;
  const int tid = threadIdx.x;
  const int c = (tid & 15) * 4, r = tid >> 4;
#pragma unroll
  for (int p = 0; p < 4; ++p) {
    const int krow = r + p * 16;
    float4 v4 = *(const float4*)&W[(size_t)(kt0 * 64 + krow) * D + nt * 64 + c];
    Tl[c + 0][krow] = f2bf(v4.x);
    Tl[c + 1][krow] = f2bf(v4.y);
    Tl[c + 2][krow] = f2bf(v4.z);
    Tl[c + 3][krow] = f2bf(v4.w);
  }
  __syncthreads();
#pragma unroll
  for (int p = 0; p < 4; ++p) {
    const int n = r + p * 16;
    s16x4 o4;
#pragma unroll
    for (int j = 0; j < 4; ++j) o4[j] = Tl[n][c + j];
    *(s16x4*)(WT + (size_t)(nt * 64 + n) * D + kt0 * 64 + c) = o4;
  }
}

// ---------------------------------------------------------------------------
// bf16 MFMA projection GEMM, all three projections in one launch (z=0/1/2).
// v3: 3-buffer rotating pipeline, ONE barrier per K-step. Per iter j:
//   vmcnt(4)  (outstanding = stages j,j+1 = 8; oldest 4 = stage of buf j%3)
//   s_barrier (every wave's stage-j completed before it entered)
//   STAGE buf (j+2)%3   (WAR safe: that buf's reads retired last iter,
//                        cross-wave retired before this barrier)
//   ds_read frags; MFMA.
// Tail stages clamped to D-32 (dummy) keep the vmcnt count uniform.
// MFMA order identical to v2 -> bit-identical output.
// ---------------------------------------------------------------------------
__global__ __launch_bounds__(256)
void proj_mfma3(const short* __restrict__ A, const short* __restrict__ WTb,
                short* __restrict__ OUTb) {
  __shared__ short As[3][4096];
  __shared__ short Bs[3][4096];
  const int z = blockIdx.z;
  const short* Bt = WTb + (size_t)z * D * D;
  short* OUT = OUTb + (size_t)z * ((size_t)BATCH * LSEQ * D);
  const int tid = threadIdx.x;
  const int l = tid & 63, w = tid >> 6;
  const int lo = l & 15, hi = l >> 4;
  const int wm = w >> 1, wn = w & 1;
  const int row0 = blockIdx.x * 128, col0 = blockIdx.y * 128;

#define STAGE(nb, ktn)                                                          \
  {                                                                             \
    const short* ga0 = A + ((size_t)(row0 + l) * D + (ktn) + w * 8);            \
    const short* gb0 = Bt + ((size_t)(col0 + l) * D + (ktn) + w * 8);           \
    __builtin_amdgcn_global_load_lds(                                           \
        (const __attribute__((address_space(1))) void*)ga0,                     \
        (__attribute__((address_space(3))) void*)&As[nb][(w * 128) * 8], 16, 0, 0); \
    __builtin_amdgcn_global_load_lds(                                           \
        (const __attribute__((address_space(1))) void*)(ga0 + 64 * D),          \
        (__attribute__((address_space(3))) void*)&As[nb][(w * 128 + 64) * 8], 16, 0, 0); \
    __builtin_amdgcn_global_load_lds(                                           \
        (const __attribute__((address_space(1))) void*)gb0,                     \
        (__attribute__((address_space(3))) void*)&Bs[nb][(w * 128) * 8], 16, 0, 0); \
    __builtin_amdgcn_global_load_lds(                                           \
        (const __attribute__((address_space(1))) void*)(gb0 + 64 * D),          \
        (__attribute__((address_space(3))) void*)&Bs[nb][(w * 128 + 64) * 8], 16, 0, 0); \
  }

  fx4 acc[4][4];
#pragma unroll
  for (int i = 0; i < 4; ++i)
#pragma unroll
    for (int j = 0; j < 4; ++j) acc[i][j] = (fx4){0.f, 0.f, 0.f, 0.f};

  // prologue: buffers 0,1 staged (8 loads/wave in flight)
  STAGE(0, 0);
  STAGE(1, 32);

  int buf = 0;
  for (int kt = 0; kt < D; kt += 32) {
    asm volatile("s_waitcnt vmcnt(4)" ::: "memory");  // my stage of buf done
    __builtin_amdgcn_s_barrier();                     // => ALL waves' stages done
    {
      // stage buf (j+2)%3 == (buf+2)%3; clamp tail to keep vmcnt uniform
      const int nxt = (buf + 2 >= 3) ? (buf - 1) : (buf + 2);
      const int ktn = (kt + 64 < D) ? (kt + 64) : (D - 32);
      STAGE(nxt, ktn);
    }
    s16x8 af[4], bfr[4];
#pragma unroll
    for (int mt = 0; mt < 4; ++mt)
      af[mt] = *(const s16x8*)&As[buf][(hi * 128 + wm * 64 + mt * 16 + lo) * 8];
#pragma unroll
    for (int nt = 0; nt < 4; ++nt)
      bfr[nt] = *(const s16x8*)&Bs[buf][(hi * 128 + wn * 64 + nt * 16 + lo) * 8];
#pragma unroll
    for (int mt = 0; mt < 4; ++mt)
#pragma unroll
      for (int nt = 0; nt < 4; ++nt)
        acc[mt][nt] = __builtin_amdgcn_mfma_f32_16x16x32_bf16(af[mt], bfr[nt], acc[mt][nt], 0, 0, 0);
    buf = (buf + 1 >= 3) ? 0 : (buf + 1);
  }
#undef STAGE

#pragma unroll
  for (int mt = 0; mt < 4; ++mt)
#pragma unroll
    for (int nt = 0; nt < 4; ++nt) {
      const size_t rbase = (size_t)(row0 + wm * 64 + mt * 16 + hi * 4);
      const int col = col0 + wn * 64 + nt * 16 + lo;
#pragma unroll
      for (int r = 0; r < 4; ++r) {
        float val = acc[mt][nt][r];
        if (z == 0) val *= 0.03125f;
        else if (z == 2) val = val / (1.f + expf(-val));
        OUT[(rbase + r) * D + col] = f2bf(val);
      }
    }
}

// ---------------------------------------------------------------------------
// k row L2-normalize, bf16 in place. One wave per row.
// ---------------------------------------------------------------------------
__global__ __launch_bounds__(256)
void knormb(short* __restrict__ kk) {
  const int lane = threadIdx.x & 63;
  const int w = threadIdx.x >> 6;
  const size_t row = (size_t)blockIdx.x * 4 + w;
  s16x8 v0 = *(const s16x8*)&kk[row * D + lane * 8];
  s16x8 v1 = *(const s16x8*)&kk[row * D + 512 + lane * 8];
  float f[16];
  float ss = 0.f;
#pragma unroll
  for (int j = 0; j < 8; ++j) {
    f[j] = bf2f((unsigned short)v0[j]);
    f[8 + j] = bf2f((unsigned short)v1[j]);
  }
#pragma unroll
  for (int j = 0; j < 16; ++j) ss += f[j] * f[j];
#pragma unroll
  for (int d = 1; d < 64; d <<= 1) ss += __shfl_xor(ss, d, 64);
  const float s = 1.f / fmaxf(sqrtf(ss), 1e-12f);
  s16x8 o0, o1;
#pragma unroll
  for (int j = 0; j < 8; ++j) {
    o0[j] = f2bf(f[j] * s);
    o1[j] = f2bf(f[8 + j] * s);
  }
  *(s16x8*)&kk[row * D + lane * 8] = o0;
  *(s16x8*)&kk[row * D + 512 + lane * 8] = o1;
}

// ---------------------------------------------------------------------------
// transpose kh [b][L][D] -> kT [b][D][L] (bf16), 64x64 tiles via LDS
// ---------------------------------------------------------------------------
__global__ __launch_bounds__(256)
void transpose_bf16(const short* __restrict__ kh, short* __restrict__ kT) {
  __shared__ short Tl[64][66];
  const int dt = blockIdx.x, lt = blockIdx.y, b = blockIdx.z;
  const int tid = threadIdx.x;
  const int c = (tid & 15) * 4, r = tid >> 4;
#pragma unroll
  for (int p = 0; p < 4; ++p) {
    const int row = r + p * 16;
    s16x4 v4 = *(const s16x4*)(kh + ((size_t)b * LSEQ + lt * 64 + row) * D + dt * 64 + c);
#pragma unroll
    for (int j = 0; j < 4; ++j) Tl[c + j][row] = v4[j];
  }
  __syncthreads();
#pragma unroll
  for (int p = 0; p < 4; ++p) {
    const int dk = r + p * 16;
    s16x4 o4;
#pragma unroll
    for (int j = 0; j < 4; ++j) o4[j] = Tl[dk][c + j];
    *(s16x4*)(kT + ((size_t)b * D + dt * 64 + dk) * LSEQ + lt * 64 + c) = o4;
  }
}

// ---------------------------------------------------------------------------
// Precompute per chunk (b,t): Minv and Tg (unchanged)
// ---------------------------------------------------------------------------
__global__ __launch_bounds__(256)
void precompute(const short* __restrict__ qh, const short* __restrict__ kh,
                const float* __restrict__ beta,
                short* __restrict__ Mg, short* __restrict__ Tg) {
  __shared__ float Ash[64 * 65];
  __shared__ float Msh[64 * 65];
  const int tid = threadIdx.x, l = tid & 63, w = tid >> 6;
  const int bt = blockIdx.x;
  const int b = bt >> 5, t = bt & 31;
  const int lo = l & 15, hi = l >> 4;
  const size_t rb = (size_t)b * LSEQ + t * 64;

  fx4 aK[4], aQ[4];
#pragma unroll
  for (int n = 0; n < 4; ++n) { aK[n] = (fx4){0,0,0,0}; aQ[n] = (fx4){0,0,0,0}; }

  const short* krow = kh + (rb + w * 16 + lo) * D;
  const short* qrow = qh + (rb + w * 16 + lo) * D;
#pragma unroll 2
  for (int ks = 0; ks < 32; ++ks) {
    s16x8 ak = *(const s16x8*)(krow + ks * 32 + hi * 8);
    s16x8 aq = *(const s16x8*)(qrow + ks * 32 + hi * 8);
#pragma unroll
    for (int n = 0; n < 4; ++n) {
      s16x8 bk = *(const s16x8*)(kh + (rb + n * 16 + lo) * D + ks * 32 + hi * 8);
      aK[n] = __builtin_amdgcn_mfma_f32_16x16x32_bf16(ak, bk, aK[n], 0, 0, 0);
      aQ[n] = __builtin_amdgcn_mfma_f32_16x16x32_bf16(aq, bk, aQ[n], 0, 0, 0);
    }
  }
#pragma unroll
  for (int n = 0; n < 4; ++n) {
#pragma unroll
    for (int r = 0; r < 4; ++r) {
      const int i = w * 16 + hi * 4 + r, s = n * 16 + lo;
      const float bi = beta[rb + i];
      Ash[i * 65 + s] = (s < i) ? bi * aK[n][r] : 0.f;
      Tg[(size_t)bt * 4096 + i * 64 + s] = (s <= i) ? f2bf(aQ[n][r]) : (short)0;
    }
  }
  __syncthreads();
  if (w == 0) {
    Msh[0 * 65 + l] = (l == 0) ? 1.f : 0.f;
    for (int i = 1; i < 64; ++i) {
      float s = 0.f;
      for (int ss = 0; ss < i; ++ss) s += Ash[i * 65 + ss] * Msh[ss * 65 + l];
      Msh[i * 65 + l] = ((i == l) ? 1.f : 0.f) - s;
    }
  }
  __syncthreads();
  {
    const int row = tid >> 2, c0 = (tid & 3) * 16;
    s16x8 o0, o1;
#pragma unroll
    for (int j = 0; j < 8; ++j) o0[j] = f2bf(Msh[row * 65 + c0 + j]);
#pragma unroll
    for (int j = 0; j < 8; ++j) o1[j] = f2bf(Msh[row * 65 + c0 + 8 + j]);
    *(s16x8*)(Mg + (size_t)bt * 4096 + row * 64 + c0) = o0;
    *(s16x8*)(Mg + (size_t)bt * 4096 + row * 64 + c0 + 8) = o1;
  }
}

// ---------------------------------------------------------------------------
// Sequential chunked scan, v9b (unchanged, 549us-config verified).
// ---------------------------------------------------------------------------
__global__ __launch_bounds__(512, 2)
void scan_chunked(const short* __restrict__ qh, const short* __restrict__ kh,
                  const short* __restrict__ vh, const short* __restrict__ kT,
                  const float* __restrict__ beta,
                  const short* __restrict__ Mg, const short* __restrict__ Tg,
                  float* __restrict__ out) {
  __shared__ __align__(16) short SB[32 * 1024];      // 64 KB [n=32][dk] swizzled
  __shared__ __align__(16) short RTs[32 * 64];       // 4 KB rhs^T
  __shared__ __align__(16) short UTs[32 * 64];       // 4 KB U^T
  __shared__ float PS_R[4][16][33];                  // 8.25 KB K@S partials
  __shared__ float PS_Y[4][16][33];                  // 8.25 KB Q@S partials
  __shared__ __align__(1024) char RING[8][4][2048];  // 64 KB: 8 waves x 4 slots
  const int tid = threadIdx.x;
  const int l = tid & 63, w = tid >> 6;
  const int lo = l & 15, hi = l >> 4;
  const int mR = w & 3;        // M-tile for P1'/P2/P3'
  const int KH = w >> 2;       // dk-half for P1'
  const int b = blockIdx.x, n0 = blockIdx.y * 32;
  const size_t bL = (size_t)b * LSEQ;
  const int swl = (lo & 7) << 4;
  const int cl = mR * 16 + hi * 4;   // chunk-local row base
  const int rsub = l >> 3;
  const int csub = l & 7;

#define WAITV4() asm volatile("s_waitcnt vmcnt(4)" ::: "memory")
#define LGKM0()  asm volatile("s_waitcnt lgkmcnt(0)" ::: "memory")

#define STAGE_KQ(PTR, slot, rowbase, dk0)                                       \
  {                                                                             \
    _Pragma("unroll")                                                           \
    for (int ii = 0; ii < 2; ++ii) {                                            \
      const int rr_ = ii * 8 + rsub;                                            \
      const short* src_ = (PTR) + (bL + (size_t)((rowbase) + rr_)) * D + (dk0)  \
                          + 8 * (csub ^ (rr_ & 7));                             \
      __builtin_amdgcn_global_load_lds(                                         \
          (const __attribute__((address_space(1))) void*)src_,                  \
          (__attribute__((address_space(3))) void*)&RING[w][slot][ii * 1024],   \
          16, 0, 0);                                                            \
    }                                                                           \
  }

#define STAGE_KT(slot, dkbase, cb)                                              \
  {                                                                             \
    _Pragma("unroll")                                                           \
    for (int ii = 0; ii < 2; ++ii) {                                            \
      const int rr_ = ii * 8 + rsub;                                            \
      const short* src_ = kT + ((size_t)b * D + (dkbase) + rr_) * LSEQ + (cb)   \
                          + 8 * (csub ^ (rr_ & 7));                             \
      __builtin_amdgcn_global_load_lds(                                         \
          (const __attribute__((address_space(1))) void*)src_,                  \
          (__attribute__((address_space(3))) void*)&RING[w][slot][ii * 1024],   \
          16, 0, 0);                                                            \
    }                                                                           \
  }

#define RF(slot, j) \
  (*(const s16x8*)&RING[w][slot][lo * 128 + (((j) * 64 + hi * 16) ^ swl)])
#define SBF(h, byteoff) \
  (*(const s16x8*)((const char*)SB + ((h) * 16 + lo) * 2048 + ((byteoff) ^ swl)))
#define RTF(h, ks) \
  (*(const s16x8*)((const char*)RTs + ((h) * 16 + lo) * 128 + ((((ks) * 32 + hi * 8) * 2) ^ swl)))
#define UTF(h, ks) \
  (*(const s16x8*)((const char*)UTs + ((h) * 16 + lo) * 128 + ((((ks) * 32 + hi * 8) * 2) ^ swl)))

  float vv[2][4], bb[4];
  s16x8 mg0, mg1, tg0, tg1;
#define LOAD_EXTRAS(tt)                                                         \
  if (KH == 0) {                                                                \
    const int r0_ = (tt) * 64;                                                  \
    const size_t mtb_ = ((size_t)(b * NCHUNK + (tt))) * 4096 + (mR * 16 + lo) * 64; \
    _Pragma("unroll")                                                           \
    for (int r = 0; r < 4; ++r) {                                               \
      vv[0][r] = bf2f((unsigned short)vh[(bL + r0_ + cl + r) * D + n0 + lo]);   \
      vv[1][r] = bf2f((unsigned short)vh[(bL + r0_ + cl + r) * D + n0 + 16 + lo]); \
      bb[r] = beta[bL + r0_ + cl + r];                                          \
    }                                                                           \
    mg0 = *(const s16x8*)(Mg + mtb_ + hi * 8);                                  \
    mg1 = *(const s16x8*)(Mg + mtb_ + 32 + hi * 8);                             \
    tg0 = *(const s16x8*)(Tg + mtb_ + hi * 8);                                  \
    tg1 = *(const s16x8*)(Tg + mtb_ + 32 + hi * 8);                             \
  }

  fx4 S[8][2];
#pragma unroll
  for (int a = 0; a < 8; ++a) {
    S[a][0] = (fx4){0.f, 0.f, 0.f, 0.f};
    S[a][1] = (fx4){0.f, 0.f, 0.f, 0.f};
  }

  for (int i = tid; i < 32 * 1024 / 2; i += 512) ((int*)SB)[i] = 0;

  LOAD_EXTRAS(0);
  asm volatile("" ::: "memory");
  STAGE_KQ(kh, 0, mR * 16, KH * 512 + 0);    // slice0 = K0
  STAGE_KQ(qh, 1, mR * 16, KH * 512 + 0);    // slice1 = Q0
  STAGE_KQ(kh, 2, mR * 16, KH * 512 + 64);   // slice2 = K1
  STAGE_KQ(qh, 3, mR * 16, KH * 512 + 64);   // slice3 = Q1
  LGKM0();
  __builtin_amdgcn_s_barrier();

  for (int t = 0; t < NCHUNK; ++t) {
    const int r0 = t * 64;
    const int rnext = (t + 1 < NCHUNK) ? (r0 + 64) : r0;

    // ---- P1': fused K@S and Q@S over own dk-half, both n-halves.
    fx4 a0 = (fx4){0,0,0,0}, a1 = (fx4){0,0,0,0}, a2 = (fx4){0,0,0,0}, a3 = (fx4){0,0,0,0};
    fx4 y0 = (fx4){0,0,0,0}, y1 = (fx4){0,0,0,0}, y2 = (fx4){0,0,0,0}, y3 = (fx4){0,0,0,0};
#pragma unroll
    for (int g = 0; g < 8; ++g) {
      WAITV4();
      const int sK = (2 * g) & 3, sQ = (2 * g + 1) & 3;
      s16x8 f0 = RF(sK, 0), f1 = RF(sK, 1);
      s16x8 q0 = RF(sQ, 0), q1 = RF(sQ, 1);
      const int dkb = (KH * 512 + g * 64) * 2 + hi * 16;
      s16x8 b0 = SBF(0, dkb), b1 = SBF(0, dkb + 64);
      s16x8 b2 = SBF(1, dkb), b3 = SBF(1, dkb + 64);
      LGKM0();
      if (g < 6) {
        STAGE_KQ(kh, sK, r0 + mR * 16, KH * 512 + (g + 2) * 64);
        STAGE_KQ(qh, sQ, r0 + mR * 16, KH * 512 + (g + 2) * 64);
      } else if (g == 6) {
        STAGE_KT(0, w * 128 + 0, r0);
        STAGE_KT(1, w * 128 + 16, r0);
      } else {
        STAGE_KT(2, w * 128 + 32, r0);
        STAGE_KT(3, w * 128 + 48, r0);
      }
      a0 = __builtin_amdgcn_mfma_f32_16x16x32_bf16(f0, b0, a0, 0, 0, 0);
      a1 = __builtin_amdgcn_mfma_f32_16x16x32_bf16(f1, b1, a1, 0, 0, 0);
      a2 = __builtin_amdgcn_mfma_f32_16x16x32_bf16(f0, b2, a2, 0, 0, 0);
      a3 = __builtin_amdgcn_mfma_f32_16x16x32_bf16(f1, b3, a3, 0, 0, 0);
      y0 = __builtin_amdgcn_mfma_f32_16x16x32_bf16(q0, b0, y0, 0, 0, 0);
      y1 = __builtin_amdgcn_mfma_f32_16x16x32_bf16(q1, b1, y1, 0, 0, 0);
      y2 = __builtin_amdgcn_mfma_f32_16x16x32_bf16(q0, b2, y2, 0, 0, 0);
      y3 = __builtin_amdgcn_mfma_f32_16x16x32_bf16(q1, b3, y3, 0, 0, 0);
    }
    if (KH == 1) {
#pragma unroll
      for (int r = 0; r < 4; ++r) {
        PS_R[mR][hi * 4 + r][lo]      = a0[r] + a1[r];
        PS_R[mR][hi * 4 + r][16 + lo] = a2[r] + a3[r];
        PS_Y[mR][hi * 4 + r][lo]      = y0[r] + y1[r];
        PS_Y[mR][hi * 4 + r][16 + lo] = y2[r] + y3[r];
      }
    }
    LGKM0();
    __builtin_amdgcn_s_barrier();   // bar A: PS ready

    if (KH == 0) {
      s16x4 p0, p1;
#pragma unroll
      for (int r = 0; r < 4; ++r) {
        p0[r] = f2bf(bb[r] * (vv[0][r] - (a0[r] + a1[r] + PS_R[mR][hi * 4 + r][lo])));
        p1[r] = f2bf(bb[r] * (vv[1][r] - (a2[r] + a3[r] + PS_R[mR][hi * 4 + r][16 + lo])));
      }
      *(s16x4*)((char*)RTs + lo * 128 + ((cl * 2) ^ swl)) = p0;
      *(s16x4*)((char*)RTs + (16 + lo) * 128 + ((cl * 2) ^ swl)) = p1;
    }
    LGKM0();
    __builtin_amdgcn_s_barrier();   // bar B: RT ready

    if (KH == 0) {
      fx4 u0 = (fx4){0,0,0,0}, u1 = (fx4){0,0,0,0};
      u0 = __builtin_amdgcn_mfma_f32_16x16x32_bf16(mg0, RTF(0, 0), u0, 0, 0, 0);
      u0 = __builtin_amdgcn_mfma_f32_16x16x32_bf16(mg1, RTF(0, 1), u0, 0, 0, 0);
      u1 = __builtin_amdgcn_mfma_f32_16x16x32_bf16(mg0, RTF(1, 0), u1, 0, 0, 0);
      u1 = __builtin_amdgcn_mfma_f32_16x16x32_bf16(mg1, RTF(1, 1), u1, 0, 0, 0);
      s16x4 p0, p1;
#pragma unroll
      for (int r = 0; r < 4; ++r) { p0[r] = f2bf(u0[r]); p1[r] = f2bf(u1[r]); }
      *(s16x4*)((char*)UTs + lo * 128 + ((cl * 2) ^ swl)) = p0;
      *(s16x4*)((char*)UTs + (16 + lo) * 128 + ((cl * 2) ^ swl)) = p1;
    }
    LGKM0();
    __builtin_amdgcn_s_barrier();   // bar C: UT ready

    const s16x8 bu00 = UTF(0, 0), bu01 = UTF(0, 1);
    const s16x8 bu10 = UTF(1, 0), bu11 = UTF(1, 1);

    if (KH == 0) {
      fx4 o0 = (fx4){0,0,0,0}, o1 = (fx4){0,0,0,0};
      o0 = __builtin_amdgcn_mfma_f32_16x16x32_bf16(tg0, bu00, o0, 0, 0, 0);
      o0 = __builtin_amdgcn_mfma_f32_16x16x32_bf16(tg1, bu01, o0, 0, 0, 0);
      o1 = __builtin_amdgcn_mfma_f32_16x16x32_bf16(tg0, bu10, o1, 0, 0, 0);
      o1 = __builtin_amdgcn_mfma_f32_16x16x32_bf16(tg1, bu11, o1, 0, 0, 0);
#pragma unroll
      for (int r = 0; r < 4; ++r) {
        out[(bL + r0 + cl + r) * D + n0 + lo] =
            o0[r] + (y0[r] + y1[r]) + PS_Y[mR][hi * 4 + r][lo];
        out[(bL + r0 + cl + r) * D + n0 + 16 + lo] =
            o1[r] + (y2[r] + y3[r]) + PS_Y[mR][hi * 4 + r][16 + lo];
      }
    }

    {
      const int tn = (t + 1 < NCHUNK) ? (t + 1) : (NCHUNK - 1);
      LOAD_EXTRAS(tn);
    }

    // ---- P4: S += kT @ U  (4 pair-groups over own dk 128-slice)
#pragma unroll
    for (int j = 0; j < 4; ++j) {
      WAITV4();
      const int sA = (2 * j) & 3, sB2 = (2 * j + 1) & 3;
      s16x8 e0 = RF(sA, 0),  e1 = RF(sA, 1);
      s16x8 e2 = RF(sB2, 0), e3 = RF(sB2, 1);
      LGKM0();
      if (j < 2) {
        STAGE_KT(sA,  w * 128 + (2 * j + 4) * 16, r0);
        STAGE_KT(sB2, w * 128 + (2 * j + 5) * 16, r0);
      } else if (j == 2) {
        STAGE_KQ(kh, sA,  rnext + mR * 16, KH * 512 + 0);
        STAGE_KQ(qh, sB2, rnext + mR * 16, KH * 512 + 0);
      } else {
        STAGE_KQ(kh, sA,  rnext + mR * 16, KH * 512 + 64);
        STAGE_KQ(qh, sB2, rnext + mR * 16, KH * 512 + 64);
      }
      S[2 * j][0] = __builtin_amdgcn_mfma_f32_16x16x32_bf16(e0, bu00, S[2 * j][0], 0, 0, 0);
      S[2 * j][0] = __builtin_amdgcn_mfma_f32_16x16x32_bf16(e1, bu01, S[2 * j][0], 0, 0, 0);
      S[2 * j][1] = __builtin_amdgcn_mfma_f32_16x16x32_bf16(e0, bu10, S[2 * j][1], 0, 0, 0);
      S[2 * j][1] = __builtin_amdgcn_mfma_f32_16x16x32_bf16(e1, bu11, S[2 * j][1], 0, 0, 0);
      S[2 * j + 1][0] = __builtin_amdgcn_mfma_f32_16x16x32_bf16(e2, bu00, S[2 * j + 1][0], 0, 0, 0);
      S[2 * j + 1][0] = __builtin_amdgcn_mfma_f32_16x16x32_bf16(e3, bu01, S[2 * j + 1][0], 0, 0, 0);
      S[2 * j + 1][1] = __builtin_amdgcn_mfma_f32_16x16x32_bf16(e2, bu10, S[2 * j + 1][1], 0, 0, 0);
      S[2 * j + 1][1] = __builtin_amdgcn_mfma_f32_16x16x32_bf16(e3, bu11, S[2 * j + 1][1], 0, 0, 0);
    }

    // ---- P5: SB = bf16(S), own dk slice (both halves)
#pragma unroll
    for (int a = 0; a < 8; ++a) {
      const int dk0 = w * 128 + a * 16 + hi * 4;
#pragma unroll
      for (int h = 0; h < 2; ++h) {
        s16x4 pk;
#pragma unroll
        for (int r = 0; r < 4; ++r) pk[r] = f2bf(S[a][h][r]);
        *(s16x4*)((char*)SB + (h * 16 + lo) * 2048 + ((dk0 * 2) ^ swl)) = pk;
      }
    }
    LGKM0();
    __builtin_amdgcn_s_barrier();   // bar D: new SB ready
  }
#undef WAITV4
#undef LGKM0
#undef STAGE_KQ
#undef STAGE_KT
#undef RF
#undef SBF
#undef RTF
#undef UTF
#undef LOAD_EXTRAS
}

// ---------------------------------------------------------------------------
// LayerNorm in place on out. One wave per row.
// ---------------------------------------------------------------------------
__global__ __launch_bounds__(256)
void ln_kernel(float* __restrict__ o, const float* __restrict__ gamma,
               const float* __restrict__ betap) {
  const int lane = threadIdx.x & 63;
  const int w = threadIdx.x >> 6;
  const size_t row = (size_t)blockIdx.x * 4 + w;
  float4 vals[4];
  float s = 0.f;
#pragma unroll
  for (int m = 0; m < 4; ++m) {
    vals[m] = *(const float4*)&o[row * D + m * 256 + lane * 4];
    s += (vals[m].x + vals[m].y) + (vals[m].z + vals[m].w);
  }
#pragma unroll
  for (int d = 1; d < 64; d <<= 1) s += __shfl_xor(s, d, 64);
  const float mu = s * (1.f / 1024.f);
  float vs = 0.f;
#pragma unroll
  for (int m = 0; m < 4; ++m) {
    float dx = vals[m].x - mu; vs += dx * dx;
    dx = vals[m].y - mu; vs += dx * dx;
    dx = vals[m].z - mu; vs += dx * dx;
    dx = vals[m].w - mu; vs += dx * dx;
  }
#pragma unroll
  for (int d = 1; d < 64; d <<= 1) vs += __shfl_xor(vs, d, 64);
  const float r = 1.f / sqrtf(vs * (1.f / 1024.f) + 1e-5f);
#pragma unroll
  for (int m = 0; m < 4; ++m) {
    const int dbase = m * 256 + lane * 4;
    float4 g4 = *(const float4*)&gamma[dbase];
    float4 b4 = *(const float4*)&betap[dbase];
    float4 y;
    y.x = (vals[m].x - mu) * r * g4.x + b4.x;
    y.y = (vals[m].y - mu) * r * g4.y + b4.y;
    y.z = (vals[m].z - mu) * r * g4.z + b4.z;
    y.w = (vals[m].w - mu) * r * g4.w + b4.w;
    *(float4*)&o[row * D + dbase] = y;
  }
}

// ---------------------------------------------------------------------------
extern "C" void kernel_launch(void* const* d_in, const int* in_sizes, int n_in,
                              void* d_out, int out_size, void* d_ws, size_t ws_size,
                              hipStream_t stream) {
  const float* x   = (const float*)d_in[0];
  const float* Wq  = (const float*)d_in[1];
  const float* Wk  = (const float*)d_in[2];
  const float* Wv  = (const float*)d_in[3];
  const float* Wb  = (const float*)d_in[4];
  const float* lng = (const float*)d_in[5];
  const float* lnb = (const float*)d_in[6];
  float* out = (float*)d_out;

  const size_t MB = 1ull << 20;
  char* wsb = (char*)d_ws;
  float* beta = (float*)wsb;                 // 64 KB
  short* Mg   = (short*)(wsb + 1 * MB);      // 2 MB
  short* Tg   = (short*)(wsb + 4 * MB);      // 2 MB
  short* WTq  = (short*)(wsb + 6 * MB);      // 3 x 2 MB contiguous (q,k,v)
  short* xh   = (short*)(wsb + 16 * MB);     // 32 MB
  short* qh   = (short*)(wsb + 64 * MB);     // 3 x 32 MB contiguous (q,k,v)
  short* kh   = (short*)(wsb + 96 * MB);
  short* vh   = (short*)(wsb + 128 * MB);
  short* kT   = (short*)(wsb + 160 * MB);

  packbeta<<<4096, 256, 0, stream>>>(x, Wb, xh, beta);
  wtrans3<<<dim3(16, 16, 3), 256, 0, stream>>>(Wq, Wk, Wv, WTq);
  proj_mfma3<<<dim3(128, 8, 3), 256, 0, stream>>>(xh, WTq, qh);
  knormb<<<4096, 256, 0, stream>>>(kh);
  transpose_bf16<<<dim3(16, 32, 8), 256, 0, stream>>>(kh, kT);
  precompute<<<256, 256, 0, stream>>>(qh, kh, beta, Mg, Tg);
  scan_chunked<<<dim3(8, 32), 512, 0, stream>>>(qh, kh, vh, kT, beta, Mg, Tg, out);
  ln_kernel<<<4096, 256, 0, stream>>>(out, lng, lnb);
}

// Round 16
// 522.291 us; speedup vs baseline: 1.1336x; 1.1336x over previous
//
#include <hip/hip_runtime.h>
#include <cstdint>
#include <cstddef>

#define D 1024
#define LSEQ 2048
#define BATCH 8
#define NCHUNK 32   // LSEQ / 64

typedef float fx4  __attribute__((ext_vector_type(4)));
typedef short s16x8 __attribute__((ext_vector_type(8)));
typedef short s16x4 __attribute__((ext_vector_type(4)));

static __device__ __forceinline__ short f2bf(float f) {
  unsigned u = __builtin_bit_cast(unsigned, f);
  u = (u + 0x7FFFu + ((u >> 16) & 1u)) >> 16;   // RNE (finite values)
  return (short)u;
}
static __device__ __forceinline__ float bf2f(unsigned short h) {
  unsigned u = ((unsigned)h) << 16;
  return __builtin_bit_cast(float, u);
}

// ---------------------------------------------------------------------------
// Fused: xh = bf16(x) AND beta = sigmoid(x . Wb). One wave per row.
// ---------------------------------------------------------------------------
__global__ __launch_bounds__(256)
void packbeta(const float* __restrict__ x, const float* __restrict__ Wb,
              short* __restrict__ xh, float* __restrict__ betao) {
  const int lane = threadIdx.x & 63;
  const int w = threadIdx.x >> 6;
  const size_t row = (size_t)blockIdx.x * 4 + w;
  float s = 0.f;
#pragma unroll
  for (int m = 0; m < 4; ++m) {
    float4 xv = *(const float4*)&x[row * D + m * 256 + lane * 4];
    float4 wv = *(const float4*)&Wb[m * 256 + lane * 4];
    s += xv.x * wv.x + xv.y * wv.y + xv.z * wv.z + xv.w * wv.w;
    s16x4 p;
    p[0] = f2bf(xv.x); p[1] = f2bf(xv.y); p[2] = f2bf(xv.z); p[3] = f2bf(xv.w);
    *(s16x4*)(xh + row * D + m * 256 + lane * 4) = p;
  }
#pragma unroll
  for (int d = 1; d < 64; d <<= 1) s += __shfl_xor(s, d, 64);
  if (lane == 0) betao[row] = 1.f / (1.f + expf(-s));
}

// ---------------------------------------------------------------------------
// W [K][N] fp32 -> WT [N][K] bf16, 64x64 tiles via LDS; z selects one of 3 W.
// ---------------------------------------------------------------------------
__global__ __launch_bounds__(256)
void wtrans3(const float* __restrict__ W0, const float* __restrict__ W1,
             const float* __restrict__ W2, short* __restrict__ WTb) {
  __shared__ short Tl[64][66];
  const float* W = blockIdx.z == 0 ? W0 : (blockIdx.z == 1 ? W1 : W2);
  short* WT = WTb + (size_t)blockIdx.z * D * D;
  const int nt = blockIdx.x, kt0 = blockIdx.y;
  const int tid = threadIdx.x;
  const int c = (tid & 15) * 4, r = tid >> 4;
#pragma unroll
  for (int p = 0; p < 4; ++p) {
    const int krow = r + p * 16;
    float4 v4 = *(const float4*)&W[(size_t)(kt0 * 64 + krow) * D + nt * 64 + c];
    Tl[c + 0][krow] = f2bf(v4.x);
    Tl[c + 1][krow] = f2bf(v4.y);
    Tl[c + 2][krow] = f2bf(v4.z);
    Tl[c + 3][krow] = f2bf(v4.w);
  }
  __syncthreads();
#pragma unroll
  for (int p = 0; p < 4; ++p) {
    const int n = r + p * 16;
    s16x4 o4;
#pragma unroll
    for (int j = 0; j < 4; ++j) o4[j] = Tl[n][c + j];
    *(s16x4*)(WT + (size_t)(nt * 64 + n) * D + kt0 * 64 + c) = o4;
  }
}

// ---------------------------------------------------------------------------
// bf16 MFMA projection GEMM, all three projections in one launch (z=0/1/2).
// v2 (round-14 verified, 225us): T3/T4 counted-vmcnt pipeline, 2 buffers,
// 2 barriers/K-step. Per K-step: vmcnt(4) -> s_barrier (own oldest stage
// provably complete BEFORE the barrier => cross-wave safe) -> ds_read frags
// -> lgkmcnt(0) -> s_barrier (reads retired => overwrite safe) ->
// STAGE(cur, kt+64) -> MFMA. Last iteration peeled with vmcnt(0).
// v3 (3-buffer, 1 barrier) REGRESSED: 48KB LDS cut occupancy 32->23%,
// MfmaUtil 19->14. Occupancy (implicit wave overlap) beats barrier removal.
// ---------------------------------------------------------------------------
__global__ __launch_bounds__(256)
void proj_mfma3(const short* __restrict__ A, const short* __restrict__ WTb,
                short* __restrict__ OUTb) {
  __shared__ short As[2][4096];
  __shared__ short Bs[2][4096];
  const int z = blockIdx.z;
  const short* Bt = WTb + (size_t)z * D * D;
  short* OUT = OUTb + (size_t)z * ((size_t)BATCH * LSEQ * D);
  const int tid = threadIdx.x;
  const int l = tid & 63, w = tid >> 6;
  const int lo = l & 15, hi = l >> 4;
  const int wm = w >> 1, wn = w & 1;
  const int row0 = blockIdx.x * 128, col0 = blockIdx.y * 128;

#define STAGE(nb, ktn)                                                          \
  {                                                                             \
    const short* ga0 = A + ((size_t)(row0 + l) * D + (ktn) + w * 8);            \
    const short* gb0 = Bt + ((size_t)(col0 + l) * D + (ktn) + w * 8);           \
    __builtin_amdgcn_global_load_lds(                                           \
        (const __attribute__((address_space(1))) void*)ga0,                     \
        (__attribute__((address_space(3))) void*)&As[nb][(w * 128) * 8], 16, 0, 0); \
    __builtin_amdgcn_global_load_lds(                                           \
        (const __attribute__((address_space(1))) void*)(ga0 + 64 * D),          \
        (__attribute__((address_space(3))) void*)&As[nb][(w * 128 + 64) * 8], 16, 0, 0); \
    __builtin_amdgcn_global_load_lds(                                           \
        (const __attribute__((address_space(1))) void*)gb0,                     \
        (__attribute__((address_space(3))) void*)&Bs[nb][(w * 128) * 8], 16, 0, 0); \
    __builtin_amdgcn_global_load_lds(                                           \
        (const __attribute__((address_space(1))) void*)(gb0 + 64 * D),          \
        (__attribute__((address_space(3))) void*)&Bs[nb][(w * 128 + 64) * 8], 16, 0, 0); \
  }

  fx4 acc[4][4];
#pragma unroll
  for (int i = 0; i < 4; ++i)
#pragma unroll
    for (int j = 0; j < 4; ++j) acc[i][j] = (fx4){0.f, 0.f, 0.f, 0.f};

  // prologue: both buffers staged, 8 loads/wave in flight
  STAGE(0, 0);
  STAGE(1, 32);

  for (int kt = 0; kt < D - 32; kt += 32) {
    const int cur = (kt >> 5) & 1;
    asm volatile("s_waitcnt vmcnt(4)" ::: "memory");  // own stage of buf cur done
    __builtin_amdgcn_s_barrier();                     // => ALL waves' stages done
    s16x8 af[4], bfr[4];
#pragma unroll
    for (int mt = 0; mt < 4; ++mt)
      af[mt] = *(const s16x8*)&As[cur][(hi * 128 + wm * 64 + mt * 16 + lo) * 8];
#pragma unroll
    for (int nt = 0; nt < 4; ++nt)
      bfr[nt] = *(const s16x8*)&Bs[cur][(hi * 128 + wn * 64 + nt * 16 + lo) * 8];
    asm volatile("s_waitcnt lgkmcnt(0)" ::: "memory");  // reads retired
    __builtin_amdgcn_s_barrier();                       // => safe to overwrite cur
    if (kt + 64 < D) STAGE(cur, kt + 64);
#pragma unroll
    for (int mt = 0; mt < 4; ++mt)
#pragma unroll
      for (int nt = 0; nt < 4; ++nt)
        acc[mt][nt] = __builtin_amdgcn_mfma_f32_16x16x32_bf16(af[mt], bfr[nt], acc[mt][nt], 0, 0, 0);
  }
  // peeled last K-step (cur = 1 for D=1024): only 4 loads outstanding
  {
    asm volatile("s_waitcnt vmcnt(0)" ::: "memory");
    __builtin_amdgcn_s_barrier();
    s16x8 af[4], bfr[4];
#pragma unroll
    for (int mt = 0; mt < 4; ++mt)
      af[mt] = *(const s16x8*)&As[1][(hi * 128 + wm * 64 + mt * 16 + lo) * 8];
#pragma unroll
    for (int nt = 0; nt < 4; ++nt)
      bfr[nt] = *(const s16x8*)&Bs[1][(hi * 128 + wn * 64 + nt * 16 + lo) * 8];
#pragma unroll
    for (int mt = 0; mt < 4; ++mt)
#pragma unroll
      for (int nt = 0; nt < 4; ++nt)
        acc[mt][nt] = __builtin_amdgcn_mfma_f32_16x16x32_bf16(af[mt], bfr[nt], acc[mt][nt], 0, 0, 0);
  }
#undef STAGE

#pragma unroll
  for (int mt = 0; mt < 4; ++mt)
#pragma unroll
    for (int nt = 0; nt < 4; ++nt) {
      const size_t rbase = (size_t)(row0 + wm * 64 + mt * 16 + hi * 4);
      const int col = col0 + wn * 64 + nt * 16 + lo;
#pragma unroll
      for (int r = 0; r < 4; ++r) {
        float val = acc[mt][nt][r];
        if (z == 0) val *= 0.03125f;
        else if (z == 2) val = val / (1.f + expf(-val));
        OUT[(rbase + r) * D + col] = f2bf(val);
      }
    }
}

// ---------------------------------------------------------------------------
// k row L2-normalize, bf16 in place. One wave per row.
// ---------------------------------------------------------------------------
__global__ __launch_bounds__(256)
void knormb(short* __restrict__ kk) {
  const int lane = threadIdx.x & 63;
  const int w = threadIdx.x >> 6;
  const size_t row = (size_t)blockIdx.x * 4 + w;
  s16x8 v0 = *(const s16x8*)&kk[row * D + lane * 8];
  s16x8 v1 = *(const s16x8*)&kk[row * D + 512 + lane * 8];
  float f[16];
  float ss = 0.f;
#pragma unroll
  for (int j = 0; j < 8; ++j) {
    f[j] = bf2f((unsigned short)v0[j]);
    f[8 + j] = bf2f((unsigned short)v1[j]);
  }
#pragma unroll
  for (int j = 0; j < 16; ++j) ss += f[j] * f[j];
#pragma unroll
  for (int d = 1; d < 64; d <<= 1) ss += __shfl_xor(ss, d, 64);
  const float s = 1.f / fmaxf(sqrtf(ss), 1e-12f);
  s16x8 o0, o1;
#pragma unroll
  for (int j = 0; j < 8; ++j) {
    o0[j] = f2bf(f[j] * s);
    o1[j] = f2bf(f[8 + j] * s);
  }
  *(s16x8*)&kk[row * D + lane * 8] = o0;
  *(s16x8*)&kk[row * D + 512 + lane * 8] = o1;
}

// ---------------------------------------------------------------------------
// transpose kh [b][L][D] -> kT [b][D][L] (bf16), 64x64 tiles via LDS
// ---------------------------------------------------------------------------
__global__ __launch_bounds__(256)
void transpose_bf16(const short* __restrict__ kh, short* __restrict__ kT) {
  __shared__ short Tl[64][66];
  const int dt = blockIdx.x, lt = blockIdx.y, b = blockIdx.z;
  const int tid = threadIdx.x;
  const int c = (tid & 15) * 4, r = tid >> 4;
#pragma unroll
  for (int p = 0; p < 4; ++p) {
    const int row = r + p * 16;
    s16x4 v4 = *(const s16x4*)(kh + ((size_t)b * LSEQ + lt * 64 + row) * D + dt * 64 + c);
#pragma unroll
    for (int j = 0; j < 4; ++j) Tl[c + j][row] = v4[j];
  }
  __syncthreads();
#pragma unroll
  for (int p = 0; p < 4; ++p) {
    const int dk = r + p * 16;
    s16x4 o4;
#pragma unroll
    for (int j = 0; j < 4; ++j) o4[j] = Tl[dk][c + j];
    *(s16x4*)(kT + ((size_t)b * D + dt * 64 + dk) * LSEQ + lt * 64 + c) = o4;
  }
}

// ---------------------------------------------------------------------------
// Precompute per chunk (b,t): Minv and Tg (unchanged)
// ---------------------------------------------------------------------------
__global__ __launch_bounds__(256)
void precompute(const short* __restrict__ qh, const short* __restrict__ kh,
                const float* __restrict__ beta,
                short* __restrict__ Mg, short* __restrict__ Tg) {
  __shared__ float Ash[64 * 65];
  __shared__ float Msh[64 * 65];
  const int tid = threadIdx.x, l = tid & 63, w = tid >> 6;
  const int bt = blockIdx.x;
  const int b = bt >> 5, t = bt & 31;
  const int lo = l & 15, hi = l >> 4;
  const size_t rb = (size_t)b * LSEQ + t * 64;

  fx4 aK[4], aQ[4];
#pragma unroll
  for (int n = 0; n < 4; ++n) { aK[n] = (fx4){0,0,0,0}; aQ[n] = (fx4){0,0,0,0}; }

  const short* krow = kh + (rb + w * 16 + lo) * D;
  const short* qrow = qh + (rb + w * 16 + lo) * D;
#pragma unroll 2
  for (int ks = 0; ks < 32; ++ks) {
    s16x8 ak = *(const s16x8*)(krow + ks * 32 + hi * 8);
    s16x8 aq = *(const s16x8*)(qrow + ks * 32 + hi * 8);
#pragma unroll
    for (int n = 0; n < 4; ++n) {
      s16x8 bk = *(const s16x8*)(kh + (rb + n * 16 + lo) * D + ks * 32 + hi * 8);
      aK[n] = __builtin_amdgcn_mfma_f32_16x16x32_bf16(ak, bk, aK[n], 0, 0, 0);
      aQ[n] = __builtin_amdgcn_mfma_f32_16x16x32_bf16(aq, bk, aQ[n], 0, 0, 0);
    }
  }
#pragma unroll
  for (int n = 0; n < 4; ++n) {
#pragma unroll
    for (int r = 0; r < 4; ++r) {
      const int i = w * 16 + hi * 4 + r, s = n * 16 + lo;
      const float bi = beta[rb + i];
      Ash[i * 65 + s] = (s < i) ? bi * aK[n][r] : 0.f;
      Tg[(size_t)bt * 4096 + i * 64 + s] = (s <= i) ? f2bf(aQ[n][r]) : (short)0;
    }
  }
  __syncthreads();
  if (w == 0) {
    Msh[0 * 65 + l] = (l == 0) ? 1.f : 0.f;
    for (int i = 1; i < 64; ++i) {
      float s = 0.f;
      for (int ss = 0; ss < i; ++ss) s += Ash[i * 65 + ss] * Msh[ss * 65 + l];
      Msh[i * 65 + l] = ((i == l) ? 1.f : 0.f) - s;
    }
  }
  __syncthreads();
  {
    const int row = tid >> 2, c0 = (tid & 3) * 16;
    s16x8 o0, o1;
#pragma unroll
    for (int j = 0; j < 8; ++j) o0[j] = f2bf(Msh[row * 65 + c0 + j]);
#pragma unroll
    for (int j = 0; j < 8; ++j) o1[j] = f2bf(Msh[row * 65 + c0 + 8 + j]);
    *(s16x8*)(Mg + (size_t)bt * 4096 + row * 64 + c0) = o0;
    *(s16x8*)(Mg + (size_t)bt * 4096 + row * 64 + c0 + 8) = o1;
  }
}

// ---------------------------------------------------------------------------
// Sequential chunked scan, v9b (unchanged, verified).
// ---------------------------------------------------------------------------
__global__ __launch_bounds__(512, 2)
void scan_chunked(const short* __restrict__ qh, const short* __restrict__ kh,
                  const short* __restrict__ vh, const short* __restrict__ kT,
                  const float* __restrict__ beta,
                  const short* __restrict__ Mg, const short* __restrict__ Tg,
                  float* __restrict__ out) {
  __shared__ __align__(16) short SB[32 * 1024];      // 64 KB [n=32][dk] swizzled
  __shared__ __align__(16) short RTs[32 * 64];       // 4 KB rhs^T
  __shared__ __align__(16) short UTs[32 * 64];       // 4 KB U^T
  __shared__ float PS_R[4][16][33];                  // 8.25 KB K@S partials
  __shared__ float PS_Y[4][16][33];                  // 8.25 KB Q@S partials
  __shared__ __align__(1024) char RING[8][4][2048];  // 64 KB: 8 waves x 4 slots
  const int tid = threadIdx.x;
  const int l = tid & 63, w = tid >> 6;
  const int lo = l & 15, hi = l >> 4;
  const int mR = w & 3;        // M-tile for P1'/P2/P3'
  const int KH = w >> 2;       // dk-half for P1'
  const int b = blockIdx.x, n0 = blockIdx.y * 32;
  const size_t bL = (size_t)b * LSEQ;
  const int swl = (lo & 7) << 4;
  const int cl = mR * 16 + hi * 4;   // chunk-local row base
  const int rsub = l >> 3;
  const int csub = l & 7;

#define WAITV4() asm volatile("s_waitcnt vmcnt(4)" ::: "memory")
#define LGKM0()  asm volatile("s_waitcnt lgkmcnt(0)" ::: "memory")

#define STAGE_KQ(PTR, slot, rowbase, dk0)                                       \
  {                                                                             \
    _Pragma("unroll")                                                           \
    for (int ii = 0; ii < 2; ++ii) {                                            \
      const int rr_ = ii * 8 + rsub;                                            \
      const short* src_ = (PTR) + (bL + (size_t)((rowbase) + rr_)) * D + (dk0)  \
                          + 8 * (csub ^ (rr_ & 7));                             \
      __builtin_amdgcn_global_load_lds(                                         \
          (const __attribute__((address_space(1))) void*)src_,                  \
          (__attribute__((address_space(3))) void*)&RING[w][slot][ii * 1024],   \
          16, 0, 0);                                                            \
    }                                                                           \
  }

#define STAGE_KT(slot, dkbase, cb)                                              \
  {                                                                             \
    _Pragma("unroll")                                                           \
    for (int ii = 0; ii < 2; ++ii) {                                            \
      const int rr_ = ii * 8 + rsub;                                            \
      const short* src_ = kT + ((size_t)b * D + (dkbase) + rr_) * LSEQ + (cb)   \
                          + 8 * (csub ^ (rr_ & 7));                             \
      __builtin_amdgcn_global_load_lds(                                         \
          (const __attribute__((address_space(1))) void*)src_,                  \
          (__attribute__((address_space(3))) void*)&RING[w][slot][ii * 1024],   \
          16, 0, 0);                                                            \
    }                                                                           \
  }

#define RF(slot, j) \
  (*(const s16x8*)&RING[w][slot][lo * 128 + (((j) * 64 + hi * 16) ^ swl)])
#define SBF(h, byteoff) \
  (*(const s16x8*)((const char*)SB + ((h) * 16 + lo) * 2048 + ((byteoff) ^ swl)))
#define RTF(h, ks) \
  (*(const s16x8*)((const char*)RTs + ((h) * 16 + lo) * 128 + ((((ks) * 32 + hi * 8) * 2) ^ swl)))
#define UTF(h, ks) \
  (*(const s16x8*)((const char*)UTs + ((h) * 16 + lo) * 128 + ((((ks) * 32 + hi * 8) * 2) ^ swl)))

  float vv[2][4], bb[4];
  s16x8 mg0, mg1, tg0, tg1;
#define LOAD_EXTRAS(tt)                                                         \
  if (KH == 0) {                                                                \
    const int r0_ = (tt) * 64;                                                  \
    const size_t mtb_ = ((size_t)(b * NCHUNK + (tt))) * 4096 + (mR * 16 + lo) * 64; \
    _Pragma("unroll")                                                           \
    for (int r = 0; r < 4; ++r) {                                               \
      vv[0][r] = bf2f((unsigned short)vh[(bL + r0_ + cl + r) * D + n0 + lo]);   \
      vv[1][r] = bf2f((unsigned short)vh[(bL + r0_ + cl + r) * D + n0 + 16 + lo]); \
      bb[r] = beta[bL + r0_ + cl + r];                                          \
    }                                                                           \
    mg0 = *(const s16x8*)(Mg + mtb_ + hi * 8);                                  \
    mg1 = *(const s16x8*)(Mg + mtb_ + 32 + hi * 8);                             \
    tg0 = *(const s16x8*)(Tg + mtb_ + hi * 8);                                  \
    tg1 = *(const s16x8*)(Tg + mtb_ + 32 + hi * 8);                             \
  }

  fx4 S[8][2];
#pragma unroll
  for (int a = 0; a < 8; ++a) {
    S[a][0] = (fx4){0.f, 0.f, 0.f, 0.f};
    S[a][1] = (fx4){0.f, 0.f, 0.f, 0.f};
  }

  for (int i = tid; i < 32 * 1024 / 2; i += 512) ((int*)SB)[i] = 0;

  LOAD_EXTRAS(0);
  asm volatile("" ::: "memory");
  STAGE_KQ(kh, 0, mR * 16, KH * 512 + 0);    // slice0 = K0
  STAGE_KQ(qh, 1, mR * 16, KH * 512 + 0);    // slice1 = Q0
  STAGE_KQ(kh, 2, mR * 16, KH * 512 + 64);   // slice2 = K1
  STAGE_KQ(qh, 3, mR * 16, KH * 512 + 64);   // slice3 = Q1
  LGKM0();
  __builtin_amdgcn_s_barrier();

  for (int t = 0; t < NCHUNK; ++t) {
    const int r0 = t * 64;
    const int rnext = (t + 1 < NCHUNK) ? (r0 + 64) : r0;

    // ---- P1': fused K@S and Q@S over own dk-half, both n-halves.
    fx4 a0 = (fx4){0,0,0,0}, a1 = (fx4){0,0,0,0}, a2 = (fx4){0,0,0,0}, a3 = (fx4){0,0,0,0};
    fx4 y0 = (fx4){0,0,0,0}, y1 = (fx4){0,0,0,0}, y2 = (fx4){0,0,0,0}, y3 = (fx4){0,0,0,0};
#pragma unroll
    for (int g = 0; g < 8; ++g) {
      WAITV4();
      const int sK = (2 * g) & 3, sQ = (2 * g + 1) & 3;
      s16x8 f0 = RF(sK, 0), f1 = RF(sK, 1);
      s16x8 q0 = RF(sQ, 0), q1 = RF(sQ, 1);
      const int dkb = (KH * 512 + g * 64) * 2 + hi * 16;
      s16x8 b0 = SBF(0, dkb), b1 = SBF(0, dkb + 64);
      s16x8 b2 = SBF(1, dkb), b3 = SBF(1, dkb + 64);
      LGKM0();
      if (g < 6) {
        STAGE_KQ(kh, sK, r0 + mR * 16, KH * 512 + (g + 2) * 64);
        STAGE_KQ(qh, sQ, r0 + mR * 16, KH * 512 + (g + 2) * 64);
      } else if (g == 6) {
        STAGE_KT(0, w * 128 + 0, r0);
        STAGE_KT(1, w * 128 + 16, r0);
      } else {
        STAGE_KT(2, w * 128 + 32, r0);
        STAGE_KT(3, w * 128 + 48, r0);
      }
      a0 = __builtin_amdgcn_mfma_f32_16x16x32_bf16(f0, b0, a0, 0, 0, 0);
      a1 = __builtin_amdgcn_mfma_f32_16x16x32_bf16(f1, b1, a1, 0, 0, 0);
      a2 = __builtin_amdgcn_mfma_f32_16x16x32_bf16(f0, b2, a2, 0, 0, 0);
      a3 = __builtin_amdgcn_mfma_f32_16x16x32_bf16(f1, b3, a3, 0, 0, 0);
      y0 = __builtin_amdgcn_mfma_f32_16x16x32_bf16(q0, b0, y0, 0, 0, 0);
      y1 = __builtin_amdgcn_mfma_f32_16x16x32_bf16(q1, b1, y1, 0, 0, 0);
      y2 = __builtin_amdgcn_mfma_f32_16x16x32_bf16(q0, b2, y2, 0, 0, 0);
      y3 = __builtin_amdgcn_mfma_f32_16x16x32_bf16(q1, b3, y3, 0, 0, 0);
    }
    if (KH == 1) {
#pragma unroll
      for (int r = 0; r < 4; ++r) {
        PS_R[mR][hi * 4 + r][lo]      = a0[r] + a1[r];
        PS_R[mR][hi * 4 + r][16 + lo] = a2[r] + a3[r];
        PS_Y[mR][hi * 4 + r][lo]      = y0[r] + y1[r];
        PS_Y[mR][hi * 4 + r][16 + lo] = y2[r] + y3[r];
      }
    }
    LGKM0();
    __builtin_amdgcn_s_barrier();   // bar A: PS ready

    if (KH == 0) {
      s16x4 p0, p1;
#pragma unroll
      for (int r = 0; r < 4; ++r) {
        p0[r] = f2bf(bb[r] * (vv[0][r] - (a0[r] + a1[r] + PS_R[mR][hi * 4 + r][lo])));
        p1[r] = f2bf(bb[r] * (vv[1][r] - (a2[r] + a3[r] + PS_R[mR][hi * 4 + r][16 + lo])));
      }
      *(s16x4*)((char*)RTs + lo * 128 + ((cl * 2) ^ swl)) = p0;
      *(s16x4*)((char*)RTs + (16 + lo) * 128 + ((cl * 2) ^ swl)) = p1;
    }
    LGKM0();
    __builtin_amdgcn_s_barrier();   // bar B: RT ready

    if (KH == 0) {
      fx4 u0 = (fx4){0,0,0,0}, u1 = (fx4){0,0,0,0};
      u0 = __builtin_amdgcn_mfma_f32_16x16x32_bf16(mg0, RTF(0, 0), u0, 0, 0, 0);
      u0 = __builtin_amdgcn_mfma_f32_16x16x32_bf16(mg1, RTF(0, 1), u0, 0, 0, 0);
      u1 = __builtin_amdgcn_mfma_f32_16x16x32_bf16(mg0, RTF(1, 0), u1, 0, 0, 0);
      u1 = __builtin_amdgcn_mfma_f32_16x16x32_bf16(mg1, RTF(1, 1), u1, 0, 0, 0);
      s16x4 p0, p1;
#pragma unroll
      for (int r = 0; r < 4; ++r) { p0[r] = f2bf(u0[r]); p1[r] = f2bf(u1[r]); }
      *(s16x4*)((char*)UTs + lo * 128 + ((cl * 2) ^ swl)) = p0;
      *(s16x4*)((char*)UTs + (16 + lo) * 128 + ((cl * 2) ^ swl)) = p1;
    }
    LGKM0();
    __builtin_amdgcn_s_barrier();   // bar C: UT ready

    const s16x8 bu00 = UTF(0, 0), bu01 = UTF(0, 1);
    const s16x8 bu10 = UTF(1, 0), bu11 = UTF(1, 1);

    if (KH == 0) {
      fx4 o0 = (fx4){0,0,0,0}, o1 = (fx4){0,0,0,0};
      o0 = __builtin_amdgcn_mfma_f32_16x16x32_bf16(tg0, bu00, o0, 0, 0, 0);
      o0 = __builtin_amdgcn_mfma_f32_16x16x32_bf16(tg1, bu01, o0, 0, 0, 0);
      o1 = __builtin_amdgcn_mfma_f32_16x16x32_bf16(tg0, bu10, o1, 0, 0, 0);
      o1 = __builtin_amdgcn_mfma_f32_16x16x32_bf16(tg1, bu11, o1, 0, 0, 0);
#pragma unroll
      for (int r = 0; r < 4; ++r) {
        out[(bL + r0 + cl + r) * D + n0 + lo] =
            o0[r] + (y0[r] + y1[r]) + PS_Y[mR][hi * 4 + r][lo];
        out[(bL + r0 + cl + r) * D + n0 + 16 + lo] =
            o1[r] + (y2[r] + y3[r]) + PS_Y[mR][hi * 4 + r][16 + lo];
      }
    }

    {
      const int tn = (t + 1 < NCHUNK) ? (t + 1) : (NCHUNK - 1);
      LOAD_EXTRAS(tn);
    }

    // ---- P4: S += kT @ U  (4 pair-groups over own dk 128-slice)
#pragma unroll
    for (int j = 0; j < 4; ++j) {
      WAITV4();
      const int sA = (2 * j) & 3, sB2 = (2 * j + 1) & 3;
      s16x8 e0 = RF(sA, 0),  e1 = RF(sA, 1);
      s16x8 e2 = RF(sB2, 0), e3 = RF(sB2, 1);
      LGKM0();
      if (j < 2) {
        STAGE_KT(sA,  w * 128 + (2 * j + 4) * 16, r0);
        STAGE_KT(sB2, w * 128 + (2 * j + 5) * 16, r0);
      } else if (j == 2) {
        STAGE_KQ(kh, sA,  rnext + mR * 16, KH * 512 + 0);
        STAGE_KQ(qh, sB2, rnext + mR * 16, KH * 512 + 0);
      } else {
        STAGE_KQ(kh, sA,  rnext + mR * 16, KH * 512 + 64);
        STAGE_KQ(qh, sB2, rnext + mR * 16, KH * 512 + 64);
      }
      S[2 * j][0] = __builtin_amdgcn_mfma_f32_16x16x32_bf16(e0, bu00, S[2 * j][0], 0, 0, 0);
      S[2 * j][0] = __builtin_amdgcn_mfma_f32_16x16x32_bf16(e1, bu01, S[2 * j][0], 0, 0, 0);
      S[2 * j][1] = __builtin_amdgcn_mfma_f32_16x16x32_bf16(e0, bu10, S[2 * j][1], 0, 0, 0);
      S[2 * j][1] = __builtin_amdgcn_mfma_f32_16x16x32_bf16(e1, bu11, S[2 * j][1], 0, 0, 0);
      S[2 * j + 1][0] = __builtin_amdgcn_mfma_f32_16x16x32_bf16(e2, bu00, S[2 * j + 1][0], 0, 0, 0);
      S[2 * j + 1][0] = __builtin_amdgcn_mfma_f32_16x16x32_bf16(e3, bu01, S[2 * j + 1][0], 0, 0, 0);
      S[2 * j + 1][1] = __builtin_amdgcn_mfma_f32_16x16x32_bf16(e2, bu10, S[2 * j + 1][1], 0, 0, 0);
      S[2 * j + 1][1] = __builtin_amdgcn_mfma_f32_16x16x32_bf16(e3, bu11, S[2 * j + 1][1], 0, 0, 0);
    }

    // ---- P5: SB = bf16(S), own dk slice (both halves)
#pragma unroll
    for (int a = 0; a < 8; ++a) {
      const int dk0 = w * 128 + a * 16 + hi * 4;
#pragma unroll
      for (int h = 0; h < 2; ++h) {
        s16x4 pk;
#pragma unroll
        for (int r = 0; r < 4; ++r) pk[r] = f2bf(S[a][h][r]);
        *(s16x4*)((char*)SB + (h * 16 + lo) * 2048 + ((dk0 * 2) ^ swl)) = pk;
      }
    }
    LGKM0();
    __builtin_amdgcn_s_barrier();   // bar D: new SB ready
  }
#undef WAITV4
#undef LGKM0
#undef STAGE_KQ
#undef STAGE_KT
#undef RF
#undef SBF
#undef RTF
#undef UTF
#undef LOAD_EXTRAS
}

// ---------------------------------------------------------------------------
// LayerNorm in place on out. One wave per row.
// ---------------------------------------------------------------------------
__global__ __launch_bounds__(256)
void ln_kernel(float* __restrict__ o, const float* __restrict__ gamma,
               const float* __restrict__ betap) {
  const int lane = threadIdx.x & 63;
  const int w = threadIdx.x >> 6;
  const size_t row = (size_t)blockIdx.x * 4 + w;
  float4 vals[4];
  float s = 0.f;
#pragma unroll
  for (int m = 0; m < 4; ++m) {
    vals[m] = *(const float4*)&o[row * D + m * 256 + lane * 4];
    s += (vals[m].x + vals[m].y) + (vals[m].z + vals[m].w);
  }
#pragma unroll
  for (int d = 1; d < 64; d <<= 1) s += __shfl_xor(s, d, 64);
  const float mu = s * (1.f / 1024.f);
  float vs = 0.f;
#pragma unroll
  for (int m = 0; m < 4; ++m) {
    float dx = vals[m].x - mu; vs += dx * dx;
    dx = vals[m].y - mu; vs += dx * dx;
    dx = vals[m].z - mu; vs += dx * dx;
    dx = vals[m].w - mu; vs += dx * dx;
  }
#pragma unroll
  for (int d = 1; d < 64; d <<= 1) vs += __shfl_xor(vs, d, 64);
  const float r = 1.f / sqrtf(vs * (1.f / 1024.f) + 1e-5f);
#pragma unroll
  for (int m = 0; m < 4; ++m) {
    const int dbase = m * 256 + lane * 4;
    float4 g4 = *(const float4*)&gamma[dbase];
    float4 b4 = *(const float4*)&betap[dbase];
    float4 y;
    y.x = (vals[m].x - mu) * r * g4.x + b4.x;
    y.y = (vals[m].y - mu) * r * g4.y + b4.y;
    y.z = (vals[m].z - mu) * r * g4.z + b4.z;
    y.w = (vals[m].w - mu) * r * g4.w + b4.w;
    *(float4*)&o[row * D + dbase] = y;
  }
}

// ---------------------------------------------------------------------------
extern "C" void kernel_launch(void* const* d_in, const int* in_sizes, int n_in,
                              void* d_out, int out_size, void* d_ws, size_t ws_size,
                              hipStream_t stream) {
  const float* x   = (const float*)d_in[0];
  const float* Wq  = (const float*)d_in[1];
  const float* Wk  = (const float*)d_in[2];
  const float* Wv  = (const float*)d_in[3];
  const float* Wb  = (const float*)d_in[4];
  const float* lng = (const float*)d_in[5];
  const float* lnb = (const float*)d_in[6];
  float* out = (float*)d_out;

  const size_t MB = 1ull << 20;
  char* wsb = (char*)d_ws;
  float* beta = (float*)wsb;                 // 64 KB
  short* Mg   = (short*)(wsb + 1 * MB);      // 2 MB
  short* Tg   = (short*)(wsb + 4 * MB);      // 2 MB
  short* WTq  = (short*)(wsb + 6 * MB);      // 3 x 2 MB contiguous (q,k,v)
  short* xh   = (short*)(wsb + 16 * MB);     // 32 MB
  short* qh   = (short*)(wsb + 64 * MB);     // 3 x 32 MB contiguous (q,k,v)
  short* kh   = (short*)(wsb + 96 * MB);
  short* vh   = (short*)(wsb + 128 * MB);
  short* kT   = (short*)(wsb + 160 * MB);

  packbeta<<<4096, 256, 0, stream>>>(x, Wb, xh, beta);
  wtrans3<<<dim3(16, 16, 3), 256, 0, stream>>>(Wq, Wk, Wv, WTq);
  proj_mfma3<<<dim3(128, 8, 3), 256, 0, stream>>>(xh, WTq, qh);
  knormb<<<4096, 256, 0, stream>>>(kh);
  transpose_bf16<<<dim3(16, 32, 8), 256, 0, stream>>>(kh, kT);
  precompute<<<256, 256, 0, stream>>>(qh, kh, beta, Mg, Tg);
  scan_chunked<<<dim3(8, 32), 512, 0, stream>>>(qh, kh, vh, kT, beta, Mg, Tg, out);
  ln_kernel<<<4096, 256, 0, stream>>>(out, lng, lnb);
}

// Round 17
// 491.351 us; speedup vs baseline: 1.2050x; 1.0630x over previous
//
#include <hip/hip_runtime.h>
#include <cstdint>
#include <cstddef>

#define D 1024
#define LSEQ 2048
#define BATCH 8
#define NCHUNK 32   // LSEQ / 64

typedef float fx4  __attribute__((ext_vector_type(4)));
typedef short s16x8 __attribute__((ext_vector_type(8)));
typedef short s16x4 __attribute__((ext_vector_type(4)));

static __device__ __forceinline__ short f2bf(float f) {
  unsigned u = __builtin_bit_cast(unsigned, f);
  u = (u + 0x7FFFu + ((u >> 16) & 1u)) >> 16;   // RNE (finite values)
  return (short)u;
}
static __device__ __forceinline__ float bf2f(unsigned short h) {
  unsigned u = ((unsigned)h) << 16;
  return __builtin_bit_cast(float, u);
}

// ---------------------------------------------------------------------------
// Fused: xh = bf16(x) AND beta = sigmoid(x . Wb). One wave per row.
// ---------------------------------------------------------------------------
__global__ __launch_bounds__(256)
void packbeta(const float* __restrict__ x, const float* __restrict__ Wb,
              short* __restrict__ xh, float* __restrict__ betao) {
  const int lane = threadIdx.x & 63;
  const int w = threadIdx.x >> 6;
  const size_t row = (size_t)blockIdx.x * 4 + w;
  float s = 0.f;
#pragma unroll
  for (int m = 0; m < 4; ++m) {
    float4 xv = *(const float4*)&x[row * D + m * 256 + lane * 4];
    float4 wv = *(const float4*)&Wb[m * 256 + lane * 4];
    s += xv.x * wv.x + xv.y * wv.y + xv.z * wv.z + xv.w * wv.w;
    s16x4 p;
    p[0] = f2bf(xv.x); p[1] = f2bf(xv.y); p[2] = f2bf(xv.z); p[3] = f2bf(xv.w);
    *(s16x4*)(xh + row * D + m * 256 + lane * 4) = p;
  }
#pragma unroll
  for (int d = 1; d < 64; d <<= 1) s += __shfl_xor(s, d, 64);
  if (lane == 0) betao[row] = 1.f / (1.f + expf(-s));
}

// ---------------------------------------------------------------------------
// W [K][N] fp32 -> WT [N][K] bf16, 64x64 tiles via LDS; z selects one of 3 W.
// ---------------------------------------------------------------------------
__global__ __launch_bounds__(256)
void wtrans3(const float* __restrict__ W0, const float* __restrict__ W1,
             const float* __restrict__ W2, short* __restrict__ WTb) {
  __shared__ short Tl[64][66];
  const float* W = blockIdx.z == 0 ? W0 : (blockIdx.z == 1 ? W1 : W2);
  short* WT = WTb + (size_t)blockIdx.z * D * D;
  const int nt = blockIdx.x, kt0 = blockIdx.y;
  const int tid = threadIdx.x;
  const int c = (tid & 15) * 4, r = tid >> 4;
#pragma unroll
  for (int p = 0; p < 4; ++p) {
    const int krow = r + p * 16;
    float4 v4 = *(const float4*)&W[(size_t)(kt0 * 64 + krow) * D + nt * 64 + c];
    Tl[c + 0][krow] = f2bf(v4.x);
    Tl[c + 1][krow] = f2bf(v4.y);
    Tl[c + 2][krow] = f2bf(v4.z);
    Tl[c + 3][krow] = f2bf(v4.w);
  }
  __syncthreads();
#pragma unroll
  for (int p = 0; p < 4; ++p) {
    const int n = r + p * 16;
    s16x4 o4;
#pragma unroll
    for (int j = 0; j < 4; ++j) o4[j] = Tl[n][c + j];
    *(s16x4*)(WT + (size_t)(nt * 64 + n) * D + kt0 * 64 + c) = o4;
  }
}

// ---------------------------------------------------------------------------
// bf16 MFMA projection GEMM, all three projections in one launch (z=0/1/2).
// v4: 128x256 tile, 8 waves (2x4 of 64x64), same proven 2-barrier counted-
// vmcnt schedule as v2 with 3 DMAs/wave/stage (A: wave w stages chunk
// kc=w&3, half=w>>2; B: kc=w&3, quarters (w>>2)*2+{0,1}), so the wait is
// vmcnt(3) (2 stages in flight = 6 outstanding; oldest 3 = my stage of cur).
// LDS 48KB -> 3 blocks x 8 waves = 24 waves/CU (vs 20). B-bytes/MFMA -25%.
// Per-output-element MFMA order identical to v2 -> bit-identical output.
// ---------------------------------------------------------------------------
__global__ __launch_bounds__(512)
void proj_mfma3(const short* __restrict__ A, const short* __restrict__ WTb,
                short* __restrict__ OUTb) {
  __shared__ short As[2][4096];   // [kc4][row128][8]
  __shared__ short Bs[2][8192];   // [kc4][row256][8]
  const int z = blockIdx.z;
  const short* Bt = WTb + (size_t)z * D * D;
  short* OUT = OUTb + (size_t)z * ((size_t)BATCH * LSEQ * D);
  const int tid = threadIdx.x;
  const int l = tid & 63, w = tid >> 6;      // 8 waves
  const int lo = l & 15, hi = l >> 4;
  const int wm = w >> 2, wn = w & 3;         // 2x4 wave grid -> 64x64 each
  const int row0 = blockIdx.x * 128, col0 = blockIdx.y * 256;
  const int kcS = w & 3, hfS = w >> 2;       // staging role

#define STAGE(nb, ktn)                                                          \
  {                                                                             \
    const short* ga = A + ((size_t)(row0 + hfS * 64 + l) * D + (ktn) + kcS * 8); \
    __builtin_amdgcn_global_load_lds(                                           \
        (const __attribute__((address_space(1))) void*)ga,                      \
        (__attribute__((address_space(3))) void*)&As[nb][kcS * 1024 + hfS * 512], 16, 0, 0); \
    const short* gb0 = Bt + ((size_t)(col0 + (hfS * 2 + 0) * 64 + l) * D + (ktn) + kcS * 8); \
    __builtin_amdgcn_global_load_lds(                                           \
        (const __attribute__((address_space(1))) void*)gb0,                     \
        (__attribute__((address_space(3))) void*)&Bs[nb][kcS * 2048 + (hfS * 2 + 0) * 512], 16, 0, 0); \
    const short* gb1 = Bt + ((size_t)(col0 + (hfS * 2 + 1) * 64 + l) * D + (ktn) + kcS * 8); \
    __builtin_amdgcn_global_load_lds(                                           \
        (const __attribute__((address_space(1))) void*)gb1,                     \
        (__attribute__((address_space(3))) void*)&Bs[nb][kcS * 2048 + (hfS * 2 + 1) * 512], 16, 0, 0); \
  }

  fx4 acc[4][4];
#pragma unroll
  for (int i = 0; i < 4; ++i)
#pragma unroll
    for (int j = 0; j < 4; ++j) acc[i][j] = (fx4){0.f, 0.f, 0.f, 0.f};

  // prologue: both buffers staged, 6 loads/wave in flight
  STAGE(0, 0);
  STAGE(1, 32);

  for (int kt = 0; kt < D - 32; kt += 32) {
    const int cur = (kt >> 5) & 1;
    asm volatile("s_waitcnt vmcnt(3)" ::: "memory");  // own stage of buf cur done
    __builtin_amdgcn_s_barrier();                     // => ALL waves' stages done
    s16x8 af[4], bfr[4];
#pragma unroll
    for (int mt = 0; mt < 4; ++mt)
      af[mt] = *(const s16x8*)&As[cur][hi * 1024 + (wm * 64 + mt * 16 + lo) * 8];
#pragma unroll
    for (int nt = 0; nt < 4; ++nt)
      bfr[nt] = *(const s16x8*)&Bs[cur][hi * 2048 + (wn * 64 + nt * 16 + lo) * 8];
    asm volatile("s_waitcnt lgkmcnt(0)" ::: "memory");  // reads retired
    __builtin_amdgcn_s_barrier();                       // => safe to overwrite cur
    if (kt + 64 < D) STAGE(cur, kt + 64);
#pragma unroll
    for (int mt = 0; mt < 4; ++mt)
#pragma unroll
      for (int nt = 0; nt < 4; ++nt)
        acc[mt][nt] = __builtin_amdgcn_mfma_f32_16x16x32_bf16(af[mt], bfr[nt], acc[mt][nt], 0, 0, 0);
  }
  // peeled last K-step (cur = 1 for D=1024): only 3 loads outstanding
  {
    asm volatile("s_waitcnt vmcnt(0)" ::: "memory");
    __builtin_amdgcn_s_barrier();
    s16x8 af[4], bfr[4];
#pragma unroll
    for (int mt = 0; mt < 4; ++mt)
      af[mt] = *(const s16x8*)&As[1][hi * 1024 + (wm * 64 + mt * 16 + lo) * 8];
#pragma unroll
    for (int nt = 0; nt < 4; ++nt)
      bfr[nt] = *(const s16x8*)&Bs[1][hi * 2048 + (wn * 64 + nt * 16 + lo) * 8];
#pragma unroll
    for (int mt = 0; mt < 4; ++mt)
#pragma unroll
      for (int nt = 0; nt < 4; ++nt)
        acc[mt][nt] = __builtin_amdgcn_mfma_f32_16x16x32_bf16(af[mt], bfr[nt], acc[mt][nt], 0, 0, 0);
  }
#undef STAGE

#pragma unroll
  for (int mt = 0; mt < 4; ++mt)
#pragma unroll
    for (int nt = 0; nt < 4; ++nt) {
      const size_t rbase = (size_t)(row0 + wm * 64 + mt * 16 + hi * 4);
      const int col = col0 + wn * 64 + nt * 16 + lo;
#pragma unroll
      for (int r = 0; r < 4; ++r) {
        float val = acc[mt][nt][r];
        if (z == 0) val *= 0.03125f;
        else if (z == 2) val = val / (1.f + expf(-val));
        OUT[(rbase + r) * D + col] = f2bf(val);
      }
    }
}

// ---------------------------------------------------------------------------
// k row L2-normalize, bf16 in place. One wave per row.
// ---------------------------------------------------------------------------
__global__ __launch_bounds__(256)
void knormb(short* __restrict__ kk) {
  const int lane = threadIdx.x & 63;
  const int w = threadIdx.x >> 6;
  const size_t row = (size_t)blockIdx.x * 4 + w;
  s16x8 v0 = *(const s16x8*)&kk[row * D + lane * 8];
  s16x8 v1 = *(const s16x8*)&kk[row * D + 512 + lane * 8];
  float f[16];
  float ss = 0.f;
#pragma unroll
  for (int j = 0; j < 8; ++j) {
    f[j] = bf2f((unsigned short)v0[j]);
    f[8 + j] = bf2f((unsigned short)v1[j]);
  }
#pragma unroll
  for (int j = 0; j < 16; ++j) ss += f[j] * f[j];
#pragma unroll
  for (int d = 1; d < 64; d <<= 1) ss += __shfl_xor(ss, d, 64);
  const float s = 1.f / fmaxf(sqrtf(ss), 1e-12f);
  s16x8 o0, o1;
#pragma unroll
  for (int j = 0; j < 8; ++j) {
    o0[j] = f2bf(f[j] * s);
    o1[j] = f2bf(f[8 + j] * s);
  }
  *(s16x8*)&kk[row * D + lane * 8] = o0;
  *(s16x8*)&kk[row * D + 512 + lane * 8] = o1;
}

// ---------------------------------------------------------------------------
// transpose kh [b][L][D] -> kT [b][D][L] (bf16), 64x64 tiles via LDS
// ---------------------------------------------------------------------------
__global__ __launch_bounds__(256)
void transpose_bf16(const short* __restrict__ kh, short* __restrict__ kT) {
  __shared__ short Tl[64][66];
  const int dt = blockIdx.x, lt = blockIdx.y, b = blockIdx.z;
  const int tid = threadIdx.x;
  const int c = (tid & 15) * 4, r = tid >> 4;
#pragma unroll
  for (int p = 0; p < 4; ++p) {
    const int row = r + p * 16;
    s16x4 v4 = *(const s16x4*)(kh + ((size_t)b * LSEQ + lt * 64 + row) * D + dt * 64 + c);
#pragma unroll
    for (int j = 0; j < 4; ++j) Tl[c + j][row] = v4[j];
  }
  __syncthreads();
#pragma unroll
  for (int p = 0; p < 4; ++p) {
    const int dk = r + p * 16;
    s16x4 o4;
#pragma unroll
    for (int j = 0; j < 4; ++j) o4[j] = Tl[dk][c + j];
    *(s16x4*)(kT + ((size_t)b * D + dt * 64 + dk) * LSEQ + lt * 64 + c) = o4;
  }
}

// ---------------------------------------------------------------------------
// Precompute per chunk (b,t): Minv and Tg (unchanged)
// ---------------------------------------------------------------------------
__global__ __launch_bounds__(256)
void precompute(const short* __restrict__ qh, const short* __restrict__ kh,
                const float* __restrict__ beta,
                short* __restrict__ Mg, short* __restrict__ Tg) {
  __shared__ float Ash[64 * 65];
  __shared__ float Msh[64 * 65];
  const int tid = threadIdx.x, l = tid & 63, w = tid >> 6;
  const int bt = blockIdx.x;
  const int b = bt >> 5, t = bt & 31;
  const int lo = l & 15, hi = l >> 4;
  const size_t rb = (size_t)b * LSEQ + t * 64;

  fx4 aK[4], aQ[4];
#pragma unroll
  for (int n = 0; n < 4; ++n) { aK[n] = (fx4){0,0,0,0}; aQ[n] = (fx4){0,0,0,0}; }

  const short* krow = kh + (rb + w * 16 + lo) * D;
  const short* qrow = qh + (rb + w * 16 + lo) * D;
#pragma unroll 2
  for (int ks = 0; ks < 32; ++ks) {
    s16x8 ak = *(const s16x8*)(krow + ks * 32 + hi * 8);
    s16x8 aq = *(const s16x8*)(qrow + ks * 32 + hi * 8);
#pragma unroll
    for (int n = 0; n < 4; ++n) {
      s16x8 bk = *(const s16x8*)(kh + (rb + n * 16 + lo) * D + ks * 32 + hi * 8);
      aK[n] = __builtin_amdgcn_mfma_f32_16x16x32_bf16(ak, bk, aK[n], 0, 0, 0);
      aQ[n] = __builtin_amdgcn_mfma_f32_16x16x32_bf16(aq, bk, aQ[n], 0, 0, 0);
    }
  }
#pragma unroll
  for (int n = 0; n < 4; ++n) {
#pragma unroll
    for (int r = 0; r < 4; ++r) {
      const int i = w * 16 + hi * 4 + r, s = n * 16 + lo;
      const float bi = beta[rb + i];
      Ash[i * 65 + s] = (s < i) ? bi * aK[n][r] : 0.f;
      Tg[(size_t)bt * 4096 + i * 64 + s] = (s <= i) ? f2bf(aQ[n][r]) : (short)0;
    }
  }
  __syncthreads();
  if (w == 0) {
    Msh[0 * 65 + l] = (l == 0) ? 1.f : 0.f;
    for (int i = 1; i < 64; ++i) {
      float s = 0.f;
      for (int ss = 0; ss < i; ++ss) s += Ash[i * 65 + ss] * Msh[ss * 65 + l];
      Msh[i * 65 + l] = ((i == l) ? 1.f : 0.f) - s;
    }
  }
  __syncthreads();
  {
    const int row = tid >> 2, c0 = (tid & 3) * 16;
    s16x8 o0, o1;
#pragma unroll
    for (int j = 0; j < 8; ++j) o0[j] = f2bf(Msh[row * 65 + c0 + j]);
#pragma unroll
    for (int j = 0; j < 8; ++j) o1[j] = f2bf(Msh[row * 65 + c0 + 8 + j]);
    *(s16x8*)(Mg + (size_t)bt * 4096 + row * 64 + c0) = o0;
    *(s16x8*)(Mg + (size_t)bt * 4096 + row * 64 + c0 + 8) = o1;
  }
}

// ---------------------------------------------------------------------------
// Sequential chunked scan, v9b (unchanged, verified).
// ---------------------------------------------------------------------------
__global__ __launch_bounds__(512, 2)
void scan_chunked(const short* __restrict__ qh, const short* __restrict__ kh,
                  const short* __restrict__ vh, const short* __restrict__ kT,
                  const float* __restrict__ beta,
                  const short* __restrict__ Mg, const short* __restrict__ Tg,
                  float* __restrict__ out) {
  __shared__ __align__(16) short SB[32 * 1024];      // 64 KB [n=32][dk] swizzled
  __shared__ __align__(16) short RTs[32 * 64];       // 4 KB rhs^T
  __shared__ __align__(16) short UTs[32 * 64];       // 4 KB U^T
  __shared__ float PS_R[4][16][33];                  // 8.25 KB K@S partials
  __shared__ float PS_Y[4][16][33];                  // 8.25 KB Q@S partials
  __shared__ __align__(1024) char RING[8][4][2048];  // 64 KB: 8 waves x 4 slots
  const int tid = threadIdx.x;
  const int l = tid & 63, w = tid >> 6;
  const int lo = l & 15, hi = l >> 4;
  const int mR = w & 3;        // M-tile for P1'/P2/P3'
  const int KH = w >> 2;       // dk-half for P1'
  const int b = blockIdx.x, n0 = blockIdx.y * 32;
  const size_t bL = (size_t)b * LSEQ;
  const int swl = (lo & 7) << 4;
  const int cl = mR * 16 + hi * 4;   // chunk-local row base
  const int rsub = l >> 3;
  const int csub = l & 7;

#define WAITV4() asm volatile("s_waitcnt vmcnt(4)" ::: "memory")
#define LGKM0()  asm volatile("s_waitcnt lgkmcnt(0)" ::: "memory")

#define STAGE_KQ(PTR, slot, rowbase, dk0)                                       \
  {                                                                             \
    _Pragma("unroll")                                                           \
    for (int ii = 0; ii < 2; ++ii) {                                            \
      const int rr_ = ii * 8 + rsub;                                            \
      const short* src_ = (PTR) + (bL + (size_t)((rowbase) + rr_)) * D + (dk0)  \
                          + 8 * (csub ^ (rr_ & 7));                             \
      __builtin_amdgcn_global_load_lds(                                         \
          (const __attribute__((address_space(1))) void*)src_,                  \
          (__attribute__((address_space(3))) void*)&RING[w][slot][ii * 1024],   \
          16, 0, 0);                                                            \
    }                                                                           \
  }

#define STAGE_KT(slot, dkbase, cb)                                              \
  {                                                                             \
    _Pragma("unroll")                                                           \
    for (int ii = 0; ii < 2; ++ii) {                                            \
      const int rr_ = ii * 8 + rsub;                                            \
      const short* src_ = kT + ((size_t)b * D + (dkbase) + rr_) * LSEQ + (cb)   \
                          + 8 * (csub ^ (rr_ & 7));                             \
      __builtin_amdgcn_global_load_lds(                                         \
          (const __attribute__((address_space(1))) void*)src_,                  \
          (__attribute__((address_space(3))) void*)&RING[w][slot][ii * 1024],   \
          16, 0, 0);                                                            \
    }                                                                           \
  }

#define RF(slot, j) \
  (*(const s16x8*)&RING[w][slot][lo * 128 + (((j) * 64 + hi * 16) ^ swl)])
#define SBF(h, byteoff) \
  (*(const s16x8*)((const char*)SB + ((h) * 16 + lo) * 2048 + ((byteoff) ^ swl)))
#define RTF(h, ks) \
  (*(const s16x8*)((const char*)RTs + ((h) * 16 + lo) * 128 + ((((ks) * 32 + hi * 8) * 2) ^ swl)))
#define UTF(h, ks) \
  (*(const s16x8*)((const char*)UTs + ((h) * 16 + lo) * 128 + ((((ks) * 32 + hi * 8) * 2) ^ swl)))

  float vv[2][4], bb[4];
  s16x8 mg0, mg1, tg0, tg1;
#define LOAD_EXTRAS(tt)                                                         \
  if (KH == 0) {                                                                \
    const int r0_ = (tt) * 64;                                                  \
    const size_t mtb_ = ((size_t)(b * NCHUNK + (tt))) * 4096 + (mR * 16 + lo) * 64; \
    _Pragma("unroll")                                                           \
    for (int r = 0; r < 4; ++r) {                                               \
      vv[0][r] = bf2f((unsigned short)vh[(bL + r0_ + cl + r) * D + n0 + lo]);   \
      vv[1][r] = bf2f((unsigned short)vh[(bL + r0_ + cl + r) * D + n0 + 16 + lo]); \
      bb[r] = beta[bL + r0_ + cl + r];                                          \
    }                                                                           \
    mg0 = *(const s16x8*)(Mg + mtb_ + hi * 8);                                  \
    mg1 = *(const s16x8*)(Mg + mtb_ + 32 + hi * 8);                             \
    tg0 = *(const s16x8*)(Tg + mtb_ + hi * 8);                                  \
    tg1 = *(const s16x8*)(Tg + mtb_ + 32 + hi * 8);                             \
  }

  fx4 S[8][2];
#pragma unroll
  for (int a = 0; a < 8; ++a) {
    S[a][0] = (fx4){0.f, 0.f, 0.f, 0.f};
    S[a][1] = (fx4){0.f, 0.f, 0.f, 0.f};
  }

  for (int i = tid; i < 32 * 1024 / 2; i += 512) ((int*)SB)[i] = 0;

  LOAD_EXTRAS(0);
  asm volatile("" ::: "memory");
  STAGE_KQ(kh, 0, mR * 16, KH * 512 + 0);    // slice0 = K0
  STAGE_KQ(qh, 1, mR * 16, KH * 512 + 0);    // slice1 = Q0
  STAGE_KQ(kh, 2, mR * 16, KH * 512 + 64);   // slice2 = K1
  STAGE_KQ(qh, 3, mR * 16, KH * 512 + 64);   // slice3 = Q1
  LGKM0();
  __builtin_amdgcn_s_barrier();

  for (int t = 0; t < NCHUNK; ++t) {
    const int r0 = t * 64;
    const int rnext = (t + 1 < NCHUNK) ? (r0 + 64) : r0;

    // ---- P1': fused K@S and Q@S over own dk-half, both n-halves.
    fx4 a0 = (fx4){0,0,0,0}, a1 = (fx4){0,0,0,0}, a2 = (fx4){0,0,0,0}, a3 = (fx4){0,0,0,0};
    fx4 y0 = (fx4){0,0,0,0}, y1 = (fx4){0,0,0,0}, y2 = (fx4){0,0,0,0}, y3 = (fx4){0,0,0,0};
#pragma unroll
    for (int g = 0; g < 8; ++g) {
      WAITV4();
      const int sK = (2 * g) & 3, sQ = (2 * g + 1) & 3;
      s16x8 f0 = RF(sK, 0), f1 = RF(sK, 1);
      s16x8 q0 = RF(sQ, 0), q1 = RF(sQ, 1);
      const int dkb = (KH * 512 + g * 64) * 2 + hi * 16;
      s16x8 b0 = SBF(0, dkb), b1 = SBF(0, dkb + 64);
      s16x8 b2 = SBF(1, dkb), b3 = SBF(1, dkb + 64);
      LGKM0();
      if (g < 6) {
        STAGE_KQ(kh, sK, r0 + mR * 16, KH * 512 + (g + 2) * 64);
        STAGE_KQ(qh, sQ, r0 + mR * 16, KH * 512 + (g + 2) * 64);
      } else if (g == 6) {
        STAGE_KT(0, w * 128 + 0, r0);
        STAGE_KT(1, w * 128 + 16, r0);
      } else {
        STAGE_KT(2, w * 128 + 32, r0);
        STAGE_KT(3, w * 128 + 48, r0);
      }
      a0 = __builtin_amdgcn_mfma_f32_16x16x32_bf16(f0, b0, a0, 0, 0, 0);
      a1 = __builtin_amdgcn_mfma_f32_16x16x32_bf16(f1, b1, a1, 0, 0, 0);
      a2 = __builtin_amdgcn_mfma_f32_16x16x32_bf16(f0, b2, a2, 0, 0, 0);
      a3 = __builtin_amdgcn_mfma_f32_16x16x32_bf16(f1, b3, a3, 0, 0, 0);
      y0 = __builtin_amdgcn_mfma_f32_16x16x32_bf16(q0, b0, y0, 0, 0, 0);
      y1 = __builtin_amdgcn_mfma_f32_16x16x32_bf16(q1, b1, y1, 0, 0, 0);
      y2 = __builtin_amdgcn_mfma_f32_16x16x32_bf16(q0, b2, y2, 0, 0, 0);
      y3 = __builtin_amdgcn_mfma_f32_16x16x32_bf16(q1, b3, y3, 0, 0, 0);
    }
    if (KH == 1) {
#pragma unroll
      for (int r = 0; r < 4; ++r) {
        PS_R[mR][hi * 4 + r][lo]      = a0[r] + a1[r];
        PS_R[mR][hi * 4 + r][16 + lo] = a2[r] + a3[r];
        PS_Y[mR][hi * 4 + r][lo]      = y0[r] + y1[r];
        PS_Y[mR][hi * 4 + r][16 + lo] = y2[r] + y3[r];
      }
    }
    LGKM0();
    __builtin_amdgcn_s_barrier();   // bar A: PS ready

    if (KH == 0) {
      s16x4 p0, p1;
#pragma unroll
      for (int r = 0; r < 4; ++r) {
        p0[r] = f2bf(bb[r] * (vv[0][r] - (a0[r] + a1[r] + PS_R[mR][hi * 4 + r][lo])));
        p1[r] = f2bf(bb[r] * (vv[1][r] - (a2[r] + a3[r] + PS_R[mR][hi * 4 + r][16 + lo])));
      }
      *(s16x4*)((char*)RTs + lo * 128 + ((cl * 2) ^ swl)) = p0;
      *(s16x4*)((char*)RTs + (16 + lo) * 128 + ((cl * 2) ^ swl)) = p1;
    }
    LGKM0();
    __builtin_amdgcn_s_barrier();   // bar B: RT ready

    if (KH == 0) {
      fx4 u0 = (fx4){0,0,0,0}, u1 = (fx4){0,0,0,0};
      u0 = __builtin_amdgcn_mfma_f32_16x16x32_bf16(mg0, RTF(0, 0), u0, 0, 0, 0);
      u0 = __builtin_amdgcn_mfma_f32_16x16x32_bf16(mg1, RTF(0, 1), u0, 0, 0, 0);
      u1 = __builtin_amdgcn_mfma_f32_16x16x32_bf16(mg0, RTF(1, 0), u1, 0, 0, 0);
      u1 = __builtin_amdgcn_mfma_f32_16x16x32_bf16(mg1, RTF(1, 1), u1, 0, 0, 0);
      s16x4 p0, p1;
#pragma unroll
      for (int r = 0; r < 4; ++r) { p0[r] = f2bf(u0[r]); p1[r] = f2bf(u1[r]); }
      *(s16x4*)((char*)UTs + lo * 128 + ((cl * 2) ^ swl)) = p0;
      *(s16x4*)((char*)UTs + (16 + lo) * 128 + ((cl * 2) ^ swl)) = p1;
    }
    LGKM0();
    __builtin_amdgcn_s_barrier();   // bar C: UT ready

    const s16x8 bu00 = UTF(0, 0), bu01 = UTF(0, 1);
    const s16x8 bu10 = UTF(1, 0), bu11 = UTF(1, 1);

    if (KH == 0) {
      fx4 o0 = (fx4){0,0,0,0}, o1 = (fx4){0,0,0,0};
      o0 = __builtin_amdgcn_mfma_f32_16x16x32_bf16(tg0, bu00, o0, 0, 0, 0);
      o0 = __builtin_amdgcn_mfma_f32_16x16x32_bf16(tg1, bu01, o0, 0, 0, 0);
      o1 = __builtin_amdgcn_mfma_f32_16x16x32_bf16(tg0, bu10, o1, 0, 0, 0);
      o1 = __builtin_amdgcn_mfma_f32_16x16x32_bf16(tg1, bu11, o1, 0, 0, 0);
#pragma unroll
      for (int r = 0; r < 4; ++r) {
        out[(bL + r0 + cl + r) * D + n0 + lo] =
            o0[r] + (y0[r] + y1[r]) + PS_Y[mR][hi * 4 + r][lo];
        out[(bL + r0 + cl + r) * D + n0 + 16 + lo] =
            o1[r] + (y2[r] + y3[r]) + PS_Y[mR][hi * 4 + r][16 + lo];
      }
    }

    {
      const int tn = (t + 1 < NCHUNK) ? (t + 1) : (NCHUNK - 1);
      LOAD_EXTRAS(tn);
    }

    // ---- P4: S += kT @ U  (4 pair-groups over own dk 128-slice)
#pragma unroll
    for (int j = 0; j < 4; ++j) {
      WAITV4();
      const int sA = (2 * j) & 3, sB2 = (2 * j + 1) & 3;
      s16x8 e0 = RF(sA, 0),  e1 = RF(sA, 1);
      s16x8 e2 = RF(sB2, 0), e3 = RF(sB2, 1);
      LGKM0();
      if (j < 2) {
        STAGE_KT(sA,  w * 128 + (2 * j + 4) * 16, r0);
        STAGE_KT(sB2, w * 128 + (2 * j + 5) * 16, r0);
      } else if (j == 2) {
        STAGE_KQ(kh, sA,  rnext + mR * 16, KH * 512 + 0);
        STAGE_KQ(qh, sB2, rnext + mR * 16, KH * 512 + 0);
      } else {
        STAGE_KQ(kh, sA,  rnext + mR * 16, KH * 512 + 64);
        STAGE_KQ(qh, sB2, rnext + mR * 16, KH * 512 + 64);
      }
      S[2 * j][0] = __builtin_amdgcn_mfma_f32_16x16x32_bf16(e0, bu00, S[2 * j][0], 0, 0, 0);
      S[2 * j][0] = __builtin_amdgcn_mfma_f32_16x16x32_bf16(e1, bu01, S[2 * j][0], 0, 0, 0);
      S[2 * j][1] = __builtin_amdgcn_mfma_f32_16x16x32_bf16(e0, bu10, S[2 * j][1], 0, 0, 0);
      S[2 * j][1] = __builtin_amdgcn_mfma_f32_16x16x32_bf16(e1, bu11, S[2 * j][1], 0, 0, 0);
      S[2 * j + 1][0] = __builtin_amdgcn_mfma_f32_16x16x32_bf16(e2, bu00, S[2 * j + 1][0], 0, 0, 0);
      S[2 * j + 1][0] = __builtin_amdgcn_mfma_f32_16x16x32_bf16(e3, bu01, S[2 * j + 1][0], 0, 0, 0);
      S[2 * j + 1][1] = __builtin_amdgcn_mfma_f32_16x16x32_bf16(e2, bu10, S[2 * j + 1][1], 0, 0, 0);
      S[2 * j + 1][1] = __builtin_amdgcn_mfma_f32_16x16x32_bf16(e3, bu11, S[2 * j + 1][1], 0, 0, 0);
    }

    // ---- P5: SB = bf16(S), own dk slice (both halves)
#pragma unroll
    for (int a = 0; a < 8; ++a) {
      const int dk0 = w * 128 + a * 16 + hi * 4;
#pragma unroll
      for (int h = 0; h < 2; ++h) {
        s16x4 pk;
#pragma unroll
        for (int r = 0; r < 4; ++r) pk[r] = f2bf(S[a][h][r]);
        *(s16x4*)((char*)SB + (h * 16 + lo) * 2048 + ((dk0 * 2) ^ swl)) = pk;
      }
    }
    LGKM0();
    __builtin_amdgcn_s_barrier();   // bar D: new SB ready
  }
#undef WAITV4
#undef LGKM0
#undef STAGE_KQ
#undef STAGE_KT
#undef RF
#undef SBF
#undef RTF
#undef UTF
#undef LOAD_EXTRAS
}

// ---------------------------------------------------------------------------
// LayerNorm in place on out. One wave per row.
// ---------------------------------------------------------------------------
__global__ __launch_bounds__(256)
void ln_kernel(float* __restrict__ o, const float* __restrict__ gamma,
               const float* __restrict__ betap) {
  const int lane = threadIdx.x & 63;
  const int w = threadIdx.x >> 6;
  const size_t row = (size_t)blockIdx.x * 4 + w;
  float4 vals[4];
  float s = 0.f;
#pragma unroll
  for (int m = 0; m < 4; ++m) {
    vals[m] = *(const float4*)&o[row * D + m * 256 + lane * 4];
    s += (vals[m].x + vals[m].y) + (vals[m].z + vals[m].w);
  }
#pragma unroll
  for (int d = 1; d < 64; d <<= 1) s += __shfl_xor(s, d, 64);
  const float mu = s * (1.f / 1024.f);
  float vs = 0.f;
#pragma unroll
  for (int m = 0; m < 4; ++m) {
    float dx = vals[m].x - mu; vs += dx * dx;
    dx = vals[m].y - mu; vs += dx * dx;
    dx = vals[m].z - mu; vs += dx * dx;
    dx = vals[m].w - mu; vs += dx * dx;
  }
#pragma unroll
  for (int d = 1; d < 64; d <<= 1) vs += __shfl_xor(vs, d, 64);
  const float r = 1.f / sqrtf(vs * (1.f / 1024.f) + 1e-5f);
#pragma unroll
  for (int m = 0; m < 4; ++m) {
    const int dbase = m * 256 + lane * 4;
    float4 g4 = *(const float4*)&gamma[dbase];
    float4 b4 = *(const float4*)&betap[dbase];
    float4 y;
    y.x = (vals[m].x - mu) * r * g4.x + b4.x;
    y.y = (vals[m].y - mu) * r * g4.y + b4.y;
    y.z = (vals[m].z - mu) * r * g4.z + b4.z;
    y.w = (vals[m].w - mu) * r * g4.w + b4.w;
    *(float4*)&o[row * D + dbase] = y;
  }
}

// ---------------------------------------------------------------------------
extern "C" void kernel_launch(void* const* d_in, const int* in_sizes, int n_in,
                              void* d_out, int out_size, void* d_ws, size_t ws_size,
                              hipStream_t stream) {
  const float* x   = (const float*)d_in[0];
  const float* Wq  = (const float*)d_in[1];
  const float* Wk  = (const float*)d_in[2];
  const float* Wv  = (const float*)d_in[3];
  const float* Wb  = (const float*)d_in[4];
  const float* lng = (const float*)d_in[5];
  const float* lnb = (const float*)d_in[6];
  float* out = (float*)d_out;

  const size_t MB = 1ull << 20;
  char* wsb = (char*)d_ws;
  float* beta = (float*)wsb;                 // 64 KB
  short* Mg   = (short*)(wsb + 1 * MB);      // 2 MB
  short* Tg   = (short*)(wsb + 4 * MB);      // 2 MB
  short* WTq  = (short*)(wsb + 6 * MB);      // 3 x 2 MB contiguous (q,k,v)
  short* xh   = (short*)(wsb + 16 * MB);     // 32 MB
  short* qh   = (short*)(wsb + 64 * MB);     // 3 x 32 MB contiguous (q,k,v)
  short* kh   = (short*)(wsb + 96 * MB);
  short* vh   = (short*)(wsb + 128 * MB);
  short* kT   = (short*)(wsb + 160 * MB);

  packbeta<<<4096, 256, 0, stream>>>(x, Wb, xh, beta);
  wtrans3<<<dim3(16, 16, 3), 256, 0, stream>>>(Wq, Wk, Wv, WTq);
  proj_mfma3<<<dim3(128, 4, 3), 512, 0, stream>>>(xh, WTq, qh);
  knormb<<<4096, 256, 0, stream>>>(kh);
  transpose_bf16<<<dim3(16, 32, 8), 256, 0, stream>>>(kh, kT);
  precompute<<<256, 256, 0, stream>>>(qh, kh, beta, Mg, Tg);
  scan_chunked<<<dim3(8, 32), 512, 0, stream>>>(qh, kh, vh, kT, beta, Mg, Tg, out);
  ln_kernel<<<4096, 256, 0, stream>>>(out, lng, lnb);
}